// Round 9
// baseline (204.514 us; speedup 1.0000x reference)
//
#include <hip/hip_runtime.h>
#include <stdint.h>
#include <stddef.h>

typedef _Float16 f16;
typedef _Float16 half8 __attribute__((ext_vector_type(8)));
typedef _Float16 half4 __attribute__((ext_vector_type(4)));
typedef float floatx4 __attribute__((ext_vector_type(4)));

__device__ __forceinline__ floatx4 mfma16(half8 a, half8 b, floatx4 c) {
    return __builtin_amdgcn_mfma_f32_16x16x32_f16(a, b, c, 0, 0, 0);
}

typedef __attribute__((address_space(3))) void       lds_void_t;
typedef const __attribute__((address_space(1))) void gconst_void_t;

// async 16B/lane global->LDS; lds dest = wave-uniform base + lane*16
__device__ __forceinline__ void async_copy16(void* lds, const void* g) {
    __builtin_amdgcn_global_load_lds((gconst_void_t*)g, (lds_void_t*)lds, 16, 0, 0);
}

// ---------------- fused pre-pass ----------------
// blocks [0,2048): convert x f32->f16 row-major
// blocks [2048,2816): transpose w_attn [1024,3072] -> wattnT [3072,1024] f16
// blocks [2816,3072): transpose w_proj [1024,1024] -> wprojT [1024,1024] f16
__global__ __launch_bounds__(256)
void prepass(const float* __restrict__ x, const float* __restrict__ w_attn,
             const float* __restrict__ w_proj,
             f16* __restrict__ xh, f16* __restrict__ wattnT, f16* __restrict__ wprojT)
{
    __shared__ __align__(16) f16 t[64][72];
    const int bid = blockIdx.x;
    if (bid < 2048) {
        const size_t i = ((size_t)bid * 256 + threadIdx.x) * 8;
        floatx4 a = *(const floatx4*)(x + i);
        floatx4 b = *(const floatx4*)(x + i + 4);
        half8 h;
        h[0]=(f16)a[0]; h[1]=(f16)a[1]; h[2]=(f16)a[2]; h[3]=(f16)a[3];
        h[4]=(f16)b[0]; h[5]=(f16)b[1]; h[6]=(f16)b[2]; h[7]=(f16)b[3];
        *(half8*)(xh + i) = h;
        return;
    }
    const float* W; f16* WT; int Nsz, bx, by;
    if (bid < 2816) {
        W = w_attn; WT = wattnT; Nsz = 3072;
        const int r = bid - 2048; by = r / 48; bx = r - by * 48;
    } else {
        W = w_proj; WT = wprojT; Nsz = 1024;
        const int r = bid - 2816; by = r >> 4; bx = r & 15;
    }
    const int k0 = by << 6;
    const int n0 = bx << 6;
    {
        const int r  = threadIdx.x >> 2;
        const int c0 = (threadIdx.x & 3) << 4;
        #pragma unroll
        for (int i = 0; i < 4; ++i) {
            const int c = c0 + (i << 2);
            floatx4 v = *(const floatx4*)(W + (size_t)(k0 + r) * Nsz + n0 + c);
            t[c + 0][r] = (f16)v[0];
            t[c + 1][r] = (f16)v[1];
            t[c + 2][r] = (f16)v[2];
            t[c + 3][r] = (f16)v[3];
        }
    }
    __syncthreads();
    {
        const int n  = threadIdx.x >> 2;
        const int kc = (threadIdx.x & 3) << 4;
        #pragma unroll
        for (int i = 0; i < 2; ++i) {
            half8 h = *(half8*)&t[n][kc + (i << 3)];
            *(half8*)(WT + (size_t)(n0 + n) * 1024 + k0 + kc + (i << 3)) = h;
        }
    }
}

// ---------------- QKV GEMM ----------------
// R9: R2-exact K-loop (stage -> vmcnt(0) -> barrier -> compute -> barrier, BK=32,
// NO prefetch — the R4 dbuf was the regression; this unbundles its epilogue win).
// Q/K tiles (n0<2048) use SWAPPED mfma operands: C^T fragment holds 4 consecutive
// d at fixed t -> half4 packed stores (4x fewer store instrs, less write
// amplification). V tiles keep original order (fragment already packs 4
// consecutive t -> half4 into V^T). Both epilogues correctness-proven in R4.
__global__ __launch_bounds__(256, 2)
void gemm_qkv(const f16* __restrict__ A, const f16* __restrict__ BT,
              const float* __restrict__ bias, f16* __restrict__ QKV)
{
    __shared__ __align__(16) f16 As[128 * 32];
    __shared__ __align__(16) f16 Bs[128 * 32];

    const int tid  = threadIdx.x;
    const int wave = tid >> 6;
    const int lane = tid & 63;
    const int quad = lane >> 4;
    const int l16  = lane & 15;
    const int wm   = (wave >> 1) * 64;
    const int wn   = (wave & 1) * 64;
    const int m0   = blockIdx.y * 128;
    const int n0   = blockIdx.x * 128;
    const int Ksz  = 1024;
    const bool isV = (n0 >= 2048);

    const int srow  = lane >> 2;
    const int skoff = (lane & 3) << 3;

    const f16* Ab = A  + (size_t)(m0 + wave * 16 + srow) * Ksz + skoff;
    const f16* Bb = BT + (size_t)(n0 + wave * 16 + srow) * Ksz + skoff;
    f16* AsW = &As[wave * 16 * 32];
    f16* BsW = &Bs[wave * 16 * 32];
    const size_t seg = (size_t)64 * Ksz;

    floatx4 acc[4][4] = {};

    for (int kc = 0; kc < Ksz; kc += 32) {
        async_copy16(AsW,           Ab + kc);
        async_copy16(AsW + 64 * 32, Ab + kc + seg);
        async_copy16(BsW,           Bb + kc);
        async_copy16(BsW + 64 * 32, Bb + kc + seg);
        asm volatile("s_waitcnt vmcnt(0)" ::: "memory");
        __syncthreads();

        half8 a[4], b[4];
        #pragma unroll
        for (int mt = 0; mt < 4; ++mt)
            a[mt] = *(const half8*)&As[(wm + mt * 16 + l16) * 32 + (quad << 3)];
        #pragma unroll
        for (int nt = 0; nt < 4; ++nt)
            b[nt] = *(const half8*)&Bs[(wn + nt * 16 + l16) * 32 + (quad << 3)];
        if (!isV) {   // swapped: acc holds C^T (rows=d, cols=t)
            #pragma unroll
            for (int mt = 0; mt < 4; ++mt)
                #pragma unroll
                for (int nt = 0; nt < 4; ++nt)
                    acc[mt][nt] = mfma16(b[nt], a[mt], acc[mt][nt]);
        } else {
            #pragma unroll
            for (int mt = 0; mt < 4; ++mt)
                #pragma unroll
                for (int nt = 0; nt < 4; ++nt)
                    acc[mt][nt] = mfma16(a[mt], b[nt], acc[mt][nt]);
        }
        __syncthreads();
    }

    const size_t HSZ = (size_t)32 * 2048 * 64;   // one of Q/K/V regions
    if (!isV) {
        // swapped layout: lane holds t = m0+wm+mt*16+l16 fixed,
        // cols = n0+wn+nt*16+quad*4 + r (4 consecutive d within one head)
        #pragma unroll
        for (int mt = 0; mt < 4; ++mt) {
            const int tg = m0 + wm + mt * 16 + l16;
            const int bb = tg >> 11;
            const int t0 = tg & 2047;
            #pragma unroll
            for (int nt = 0; nt < 4; ++nt) {
                const int colbase = n0 + wn + nt * 16 + (quad << 2);
                const floatx4 bv = *(const floatx4*)(bias + colbase);
                const int reg = colbase >> 10;        // 0 = Q, 1 = K
                const int hh  = (colbase >> 6) & 15;
                const int d0  = colbase & 63;
                half4 h;
                h[0] = (f16)(acc[mt][nt][0] + bv[0]);
                h[1] = (f16)(acc[mt][nt][1] + bv[1]);
                h[2] = (f16)(acc[mt][nt][2] + bv[2]);
                h[3] = (f16)(acc[mt][nt][3] + bv[3]);
                *(half4*)(QKV + (size_t)reg * HSZ
                          + (((size_t)(bb * 16 + hh) * 2048 + t0) << 6) + d0) = h;
            }
        }
    } else {
        // original layout: lane holds col=d fixed, 4 consecutive t -> V^T half4
        #pragma unroll
        for (int mt = 0; mt < 4; ++mt) {
            #pragma unroll
            for (int nt = 0; nt < 4; ++nt) {
                const int col  = n0 + wn + nt * 16 + l16;
                const float bv = bias[col];
                const int row0 = m0 + wm + mt * 16 + (quad << 2);
                const int bb   = row0 >> 11;
                const int t0   = row0 & 2047;
                const int hh   = (col >> 6) & 15;
                const int d    = col & 63;
                half4 h;
                h[0] = (f16)(acc[mt][nt][0] + bv);
                h[1] = (f16)(acc[mt][nt][1] + bv);
                h[2] = (f16)(acc[mt][nt][2] + bv);
                h[3] = (f16)(acc[mt][nt][3] + bv);
                *(half4*)(QKV + 2 * HSZ
                          + (((size_t)(bb * 16 + hh) << 6) + d) * 2048 + t0) = h;
            }
        }
    }
}

// ---------------- proj GEMM: 128x64 tile (512 blocks = 2/CU) ----------------
// R9: R2-exact K-loop; swapped operands -> float4 C stores (4x fewer store
// instrs). Epilogue correctness-proven in R4.
__global__ __launch_bounds__(256, 2)
void gemm_proj(const f16* __restrict__ A, const f16* __restrict__ BT,
               const float* __restrict__ bias, float* __restrict__ C)
{
    __shared__ __align__(16) f16 As[128 * 32];
    __shared__ __align__(16) f16 Bs[64 * 32];

    const int tid  = threadIdx.x;
    const int wave = tid >> 6;
    const int lane = tid & 63;
    const int quad = lane >> 4;
    const int l16  = lane & 15;
    const int wm   = (wave >> 1) * 64;
    const int wn   = (wave & 1) * 32;
    const int m0   = blockIdx.y * 128;
    const int n0   = blockIdx.x * 64;
    const int Ksz  = 1024;

    const int srow  = lane >> 2;
    const int skoff = (lane & 3) << 3;

    const f16* Ab = A  + (size_t)(m0 + wave * 16 + srow) * Ksz + skoff;
    const f16* Bb = BT + (size_t)(n0 + wave * 16 + srow) * Ksz + skoff;
    f16* AsW = &As[wave * 16 * 32];
    f16* BsW = &Bs[wave * 16 * 32];
    const size_t seg = (size_t)64 * Ksz;

    floatx4 acc[4][2] = {};

    for (int kc = 0; kc < Ksz; kc += 32) {
        async_copy16(AsW,           Ab + kc);
        async_copy16(AsW + 64 * 32, Ab + kc + seg);
        async_copy16(BsW,           Bb + kc);
        asm volatile("s_waitcnt vmcnt(0)" ::: "memory");
        __syncthreads();

        half8 a[4], b[2];
        #pragma unroll
        for (int mt = 0; mt < 4; ++mt)
            a[mt] = *(const half8*)&As[(wm + mt * 16 + l16) * 32 + (quad << 3)];
        #pragma unroll
        for (int nt = 0; nt < 2; ++nt)
            b[nt] = *(const half8*)&Bs[(wn + nt * 16 + l16) * 32 + (quad << 3)];
        #pragma unroll
        for (int mt = 0; mt < 4; ++mt)
            #pragma unroll
            for (int nt = 0; nt < 2; ++nt)
                acc[mt][nt] = mfma16(b[nt], a[mt], acc[mt][nt]);   // swapped -> C^T frag
        __syncthreads();
    }

    #pragma unroll
    for (int mt = 0; mt < 4; ++mt) {
        const int tg = m0 + wm + mt * 16 + l16;
        #pragma unroll
        for (int nt = 0; nt < 2; ++nt) {
            const int colbase = n0 + wn + nt * 16 + (quad << 2);
            const floatx4 bv = *(const floatx4*)(bias + colbase);
            floatx4 v;
            v[0] = acc[mt][nt][0] + bv[0];
            v[1] = acc[mt][nt][1] + bv[1];
            v[2] = acc[mt][nt][2] + bv[2];
            v[3] = acc[mt][nt][3] + bv[3];
            *(floatx4*)(C + (size_t)tg * 1024 + colbase) = v;
        }
    }
}

// ---------------- Flash attention, causal — FUSED DUAL-TILE COMPUTE (R8) ------
// time = chains x chain-cost; 34 dual chains/CU x ~3700cy = 52.4us (measured).
// compute2() processes BOTH q-tiles in ONE chain — interleaved QK MFMAs, exp for
// both, P-writes to two LDS buffers, ONE lgkmcnt(0), shared V fragments.
// Adjacent pairing (jA=2g, jB=2g+1); CU balance: blocks g and 15-g.
// bh-fastest grid (XCD-confined K/V), Vt 4-buf DMA 2 ahead, barrier per 2
// chunks, setprio around MFMA, swizzled V/P LDS.
__global__ __launch_bounds__(256, 2)
void attn_fwd(const f16* __restrict__ Qb, const f16* __restrict__ Kb,
              const f16* __restrict__ Vb, f16* __restrict__ attn_out)
{
    const int bh   = blockIdx.x;     // 0..31
    const int yy   = blockIdx.y;     // 0..15
    const int g    = (yy < 8) ? yy : 23 - yy;   // group 0..15; CU-pair g with 15-g
    const int jA   = 2 * g;          // even q-tile
    const int jB   = 2 * g + 1;      // odd q-tile (scan length)
    const int head = bh & 15;
    const int b    = bh >> 4;
    const int tid  = threadIdx.x;
    const int wave = tid >> 6;
    const int lane = tid & 63;
    const int quad = lane >> 4;
    const int l16  = lane & 15;

    __shared__ __align__(16) f16 Vt[4][64 * 64];   // [buf][d][kv], kv chunk8 ^ (d&7)
    __shared__ __align__(16) f16 PsB[4][16 * 64];  // per-wave P[q][kv] for tile B
    __shared__ __align__(16) f16 PsA[4][16 * 64];  // per-wave P[q][kv] for tile A

    const f16* Qh = Qb + ((size_t)bh << 17);
    const f16* Kh = Kb + ((size_t)bh << 17);
    const f16* Vh = Vb + ((size_t)bh << 17);

    // V DMA: wave stages d rows 16w..16w+15; instr g covers rows +8g..+8g+7.
    // lane L -> d-row r8=L>>3, source kv-chunk c8=(L&7)^r8 (XOR-swizzled LDS).
    const int r8 = lane >> 3;
    const int c8 = (lane & 7) ^ r8;
    const f16* vsrcA = Vh + (size_t)(wave * 16 + r8) * 2048 + c8 * 8;
    const f16* vsrcB = vsrcA + (size_t)8 * 2048;

    half8 kf[8], kn[8];
    half8 qA0, qA1, qB0, qB1;
    floatx4 oA[4], oB[4];
    float lpA, lpB;

    auto loadK = [&](int kv0, half8* dst) {
        const f16* kp = Kh + (size_t)(kv0 + l16) * 64 + (quad << 3);
        #pragma unroll
        for (int t = 0; t < 4; ++t) {
            dst[2 * t]     = *(const half8*)(kp + t * 16 * 64);
            dst[2 * t + 1] = *(const half8*)(kp + t * 16 * 64 + 32);
        }
    };
    auto dmaV = [&](int kv0, int buf) {
        async_copy16(&Vt[buf][(wave * 16) * 64],     vsrcA + kv0);
        async_copy16(&Vt[buf][(wave * 16 + 8) * 64], vsrcB + kv0);
    };

    const int sw = l16 & 7;   // swizzle key (= d&7 and q&7 for our rows)

    // BOTH q-tiles in one chain: interleaved QK, one lgkm wait, shared V frags.
    // Precondition: kc < jB (tile B never diagonal here); diagA = (kc == jA).
    auto compute2 = [&](int kc, bool diagA, half8* kcur) {
        floatx4 sB[4] = {};
        floatx4 sA[4] = {};
        __builtin_amdgcn_s_setprio(1);
        #pragma unroll
        for (int t = 0; t < 4; ++t) {
            sB[t] = mfma16(kcur[2 * t],     qB0, sB[t]);
            sA[t] = mfma16(kcur[2 * t],     qA0, sA[t]);
            sB[t] = mfma16(kcur[2 * t + 1], qB1, sB[t]);
            sA[t] = mfma16(kcur[2 * t + 1], qA1, sA[t]);
        }
        __builtin_amdgcn_s_setprio(0);
        const int qrel = (wave << 4) + l16;
        #pragma unroll
        for (int t = 0; t < 4; ++t) {
            const int c = t * 2 + (quad >> 1);
            const int po = (l16 << 6) + ((c ^ sw) << 3) + ((quad & 1) << 2);
            float b0 = __builtin_amdgcn_exp2f(sB[t][0]);
            float b1 = __builtin_amdgcn_exp2f(sB[t][1]);
            float b2 = __builtin_amdgcn_exp2f(sB[t][2]);
            float b3 = __builtin_amdgcn_exp2f(sB[t][3]);
            lpB += (b0 + b1) + (b2 + b3);
            half4 pkB; pkB[0]=(f16)b0; pkB[1]=(f16)b1; pkB[2]=(f16)b2; pkB[3]=(f16)b3;
            *(half4*)&PsB[wave][po] = pkB;
            float a0 = __builtin_amdgcn_exp2f(sA[t][0]);
            float a1 = __builtin_amdgcn_exp2f(sA[t][1]);
            float a2 = __builtin_amdgcn_exp2f(sA[t][2]);
            float a3 = __builtin_amdgcn_exp2f(sA[t][3]);
            if (diagA) {
                const int kvb = t * 16 + (quad << 2);
                a0 = (kvb     <= qrel) ? a0 : 0.f;
                a1 = (kvb + 1 <= qrel) ? a1 : 0.f;
                a2 = (kvb + 2 <= qrel) ? a2 : 0.f;
                a3 = (kvb + 3 <= qrel) ? a3 : 0.f;
            }
            lpA += (a0 + a1) + (a2 + a3);
            half4 pkA; pkA[0]=(f16)a0; pkA[1]=(f16)a1; pkA[2]=(f16)a2; pkA[3]=(f16)a3;
            *(half4*)&PsA[wave][po] = pkA;
        }
        asm volatile("s_waitcnt lgkmcnt(0)" ::: "memory");
        half8 pB0 = *(const half8*)&PsB[wave][(l16 << 6) + (((quad    ) ^ sw) << 3)];
        half8 pB1 = *(const half8*)&PsB[wave][(l16 << 6) + (((quad + 4) ^ sw) << 3)];
        half8 pA0 = *(const half8*)&PsA[wave][(l16 << 6) + (((quad    ) ^ sw) << 3)];
        half8 pA1 = *(const half8*)&PsA[wave][(l16 << 6) + (((quad + 4) ^ sw) << 3)];
        const f16* vbuf = &Vt[kc & 3][0];
        __builtin_amdgcn_s_setprio(1);
        #pragma unroll
        for (int dt = 0; dt < 4; ++dt) {
            const f16* vrow = vbuf + ((dt * 16 + l16) << 6);
            half8 vf0 = *(const half8*)(vrow + (((quad    ) ^ sw) << 3));
            half8 vf1 = *(const half8*)(vrow + (((quad + 4) ^ sw) << 3));
            oB[dt] = mfma16(pB0, vf0, oB[dt]);
            oA[dt] = mfma16(pA0, vf0, oA[dt]);
            oB[dt] = mfma16(pB1, vf1, oB[dt]);
            oA[dt] = mfma16(pA1, vf1, oA[dt]);
        }
        __builtin_amdgcn_s_setprio(0);
    };

    // single-tile chunk (B-only tail), diag = (kc == jB)
    auto compute1 = [&](int kc, half8* kcur) {
        floatx4 s[4] = {};
        __builtin_amdgcn_s_setprio(1);
        #pragma unroll
        for (int t = 0; t < 4; ++t) {
            s[t] = mfma16(kcur[2 * t],     qB0, s[t]);
            s[t] = mfma16(kcur[2 * t + 1], qB1, s[t]);
        }
        __builtin_amdgcn_s_setprio(0);
        const bool diag = (kc == jB);
        const int qrel = (wave << 4) + l16;
        #pragma unroll
        for (int t = 0; t < 4; ++t) {
            float p0 = __builtin_amdgcn_exp2f(s[t][0]);
            float p1 = __builtin_amdgcn_exp2f(s[t][1]);
            float p2 = __builtin_amdgcn_exp2f(s[t][2]);
            float p3 = __builtin_amdgcn_exp2f(s[t][3]);
            if (diag) {
                const int kvb = t * 16 + (quad << 2);
                p0 = (kvb     <= qrel) ? p0 : 0.f;
                p1 = (kvb + 1 <= qrel) ? p1 : 0.f;
                p2 = (kvb + 2 <= qrel) ? p2 : 0.f;
                p3 = (kvb + 3 <= qrel) ? p3 : 0.f;
            }
            lpB += (p0 + p1) + (p2 + p3);
            half4 pk; pk[0]=(f16)p0; pk[1]=(f16)p1; pk[2]=(f16)p2; pk[3]=(f16)p3;
            const int c = t * 2 + (quad >> 1);
            *(half4*)&PsB[wave][(l16 << 6) + ((c ^ sw) << 3) + ((quad & 1) << 2)] = pk;
        }
        asm volatile("s_waitcnt lgkmcnt(0)" ::: "memory");
        half8 pf0 = *(const half8*)&PsB[wave][(l16 << 6) + (((quad    ) ^ sw) << 3)];
        half8 pf1 = *(const half8*)&PsB[wave][(l16 << 6) + (((quad + 4) ^ sw) << 3)];
        const f16* vbuf = &Vt[kc & 3][0];
        __builtin_amdgcn_s_setprio(1);
        #pragma unroll
        for (int dt = 0; dt < 4; ++dt) {
            const f16* vrow = vbuf + ((dt * 16 + l16) << 6);
            half8 vf0 = *(const half8*)(vrow + (((quad    ) ^ sw) << 3));
            half8 vf1 = *(const half8*)(vrow + (((quad + 4) ^ sw) << 3));
            oB[dt] = mfma16(pf0, vf0, oB[dt]);
            oB[dt] = mfma16(pf1, vf1, oB[dt]);
        }
        __builtin_amdgcn_s_setprio(0);
    };

    const f16 qs = (f16)0.1803368801f;   // (1/8) * log2(e)
    auto loadQ = [&](int j, half8& q0, half8& q1) {
        const f16* qp = Qh + (size_t)(j * 64 + wave * 16 + l16) * 64 + (quad << 3);
        q0 = *(const half8*)qp;
        q1 = *(const half8*)(qp + 32);
        #pragma unroll
        for (int i = 0; i < 8; ++i) { q0[i] *= qs; q1[i] *= qs; }
    };

    loadQ(jA, qA0, qA1);
    loadQ(jB, qB0, qB1);
    oA[0]=oA[1]=oA[2]=oA[3] = (floatx4){0.f,0.f,0.f,0.f};
    oB[0]=oB[1]=oB[2]=oB[3] = (floatx4){0.f,0.f,0.f,0.f};
    lpA = 0.f; lpB = 0.f;

    const int nB = jB + 1;   // = 2g+2 >= 2, always even
    loadK(0, kf);
    dmaV(0, 0);
    dmaV(64, 1);

    // pair loop: one barrier per TWO chunks; DMA chunks kc+2/kc+3 at pair top.
    // Even kc <= jA always -> compute2 (diagA iff kc==jA). Odd kc+1: compute2
    // while kc+1 <= jA (never diagonal, parity), else compute1 (B diag tail).
    for (int kc = 0; kc < nB; kc += 2) {
        __syncthreads();
        if (kc + 2 < nB) dmaV((kc + 2) << 6, (kc + 2) & 3);
        if (kc + 3 < nB) dmaV((kc + 3) << 6, (kc + 3) & 3);
        if (kc + 1 < nB) loadK((kc + 1) << 6, kn);
        compute2(kc, kc == jA, kf);
        if (kc + 1 < nB) {
            if (kc + 2 < nB) loadK((kc + 2) << 6, kf);
            if (kc + 1 <= jA) compute2(kc + 1, false, kn);
            else               compute1(kc + 1, kn);
        }
    }

    // epilogue per q-tile: reduce l over quads, transpose inv via shuffles, write O
    auto writeO = [&](int j, floatx4* o, float lp) {
        float l = lp;
        l += __shfl_xor(l, 16);
        l += __shfl_xor(l, 32);
        const float inv = 1.f / l;
        const int qrow0 = j * 64 + wave * 16;
        #pragma unroll
        for (int r = 0; r < 4; ++r) {
            const float invr = __shfl(inv, (quad << 2) + r);
            const int row = (b << 11) + qrow0 + (quad << 2) + r;
            f16* op = attn_out + (size_t)row * 1024 + head * 64 + l16;
            #pragma unroll
            for (int dt = 0; dt < 4; ++dt)
                op[dt * 16] = (f16)(o[dt][r] * invr);
        }
    };
    writeO(jB, oB, lpB);
    writeO(jA, oA, lpA);
}

extern "C" void kernel_launch(void* const* d_in, const int* in_sizes, int n_in,
                              void* d_out, int out_size, void* d_ws, size_t ws_size,
                              hipStream_t stream)
{
    const float* x      = (const float*)d_in[0];
    const float* w_attn = (const float*)d_in[1];
    const float* b_attn = (const float*)d_in[2];
    const float* w_proj = (const float*)d_in[3];
    const float* b_proj = (const float*)d_in[4];
    float* y = (float*)d_out;

    f16* xh       = (f16*)d_ws;                         // [4096,1024]
    f16* wattnT   = xh + (size_t)4096 * 1024;           // [3072,1024]
    f16* wprojT   = wattnT + (size_t)3072 * 1024;       // [1024,1024]
    f16* qkv      = wprojT + (size_t)1024 * 1024;       // Q,K: [32][2048][64]; V: [32][64][2048]
    f16* attn_out = qkv + (size_t)3 * 32 * 2048 * 64;   // [4096,1024]

    const size_t HSZ = (size_t)32 * 2048 * 64;

    prepass<<<dim3(3072), dim3(256), 0, stream>>>(x, w_attn, w_proj, xh, wattnT, wprojT);
    gemm_qkv<<<dim3(24, 32), dim3(256), 0, stream>>>(xh, wattnT, b_attn, qkv);
    attn_fwd<<<dim3(32, 16), dim3(256), 0, stream>>>(qkv, qkv + HSZ, qkv + 2 * HSZ, attn_out);
    gemm_proj<<<dim3(16, 32), dim3(256), 0, stream>>>(attn_out, wprojT, b_proj, y);
}

// Round 10
// 190.403 us; speedup vs baseline: 1.0741x; 1.0741x over previous
//
#include <hip/hip_runtime.h>
#include <stdint.h>
#include <stddef.h>

typedef _Float16 f16;
typedef _Float16 half8 __attribute__((ext_vector_type(8)));
typedef _Float16 half4 __attribute__((ext_vector_type(4)));
typedef float floatx4 __attribute__((ext_vector_type(4)));

__device__ __forceinline__ floatx4 mfma16(half8 a, half8 b, floatx4 c) {
    return __builtin_amdgcn_mfma_f32_16x16x32_f16(a, b, c, 0, 0, 0);
}

typedef __attribute__((address_space(3))) void       lds_void_t;
typedef const __attribute__((address_space(1))) void gconst_void_t;

// async 16B/lane global->LDS; lds dest = wave-uniform base + lane*16
__device__ __forceinline__ void async_copy16(void* lds, const void* g) {
    __builtin_amdgcn_global_load_lds((gconst_void_t*)g, (lds_void_t*)lds, 16, 0, 0);
}

// ---------------- fused pre-pass ----------------
// blocks [0,2048): convert x f32->f16 row-major
// blocks [2048,2816): transpose w_attn [1024,3072] -> wattnT [3072,1024] f16
// blocks [2816,3072): transpose w_proj [1024,1024] -> wprojT [1024,1024] f16
__global__ __launch_bounds__(256)
void prepass(const float* __restrict__ x, const float* __restrict__ w_attn,
             const float* __restrict__ w_proj,
             f16* __restrict__ xh, f16* __restrict__ wattnT, f16* __restrict__ wprojT)
{
    __shared__ __align__(16) f16 t[64][72];
    const int bid = blockIdx.x;
    if (bid < 2048) {
        const size_t i = ((size_t)bid * 256 + threadIdx.x) * 8;
        floatx4 a = *(const floatx4*)(x + i);
        floatx4 b = *(const floatx4*)(x + i + 4);
        half8 h;
        h[0]=(f16)a[0]; h[1]=(f16)a[1]; h[2]=(f16)a[2]; h[3]=(f16)a[3];
        h[4]=(f16)b[0]; h[5]=(f16)b[1]; h[6]=(f16)b[2]; h[7]=(f16)b[3];
        *(half8*)(xh + i) = h;
        return;
    }
    const float* W; f16* WT; int Nsz, bx, by;
    if (bid < 2816) {
        W = w_attn; WT = wattnT; Nsz = 3072;
        const int r = bid - 2048; by = r / 48; bx = r - by * 48;
    } else {
        W = w_proj; WT = wprojT; Nsz = 1024;
        const int r = bid - 2816; by = r >> 4; bx = r & 15;
    }
    const int k0 = by << 6;
    const int n0 = bx << 6;
    {
        const int r  = threadIdx.x >> 2;
        const int c0 = (threadIdx.x & 3) << 4;
        #pragma unroll
        for (int i = 0; i < 4; ++i) {
            const int c = c0 + (i << 2);
            floatx4 v = *(const floatx4*)(W + (size_t)(k0 + r) * Nsz + n0 + c);
            t[c + 0][r] = (f16)v[0];
            t[c + 1][r] = (f16)v[1];
            t[c + 2][r] = (f16)v[2];
            t[c + 3][r] = (f16)v[3];
        }
    }
    __syncthreads();
    {
        const int n  = threadIdx.x >> 2;
        const int kc = (threadIdx.x & 3) << 4;
        #pragma unroll
        for (int i = 0; i < 2; ++i) {
            half8 h = *(half8*)&t[n][kc + (i << 3)];
            *(half8*)(WT + (size_t)(n0 + n) * 1024 + k0 + kc + (i << 3)) = h;
        }
    }
}

// ---------------- QKV GEMM ----------------
// R10: R2 epilogue (coalesced scalar Q/K stores, half4 V — R9 proved swapped
// epilogues hurt via scattered stores) + ISOLATED minimum-2-phase K-loop:
// stage(buf^1, kc+32) at top (writes other buffer, no hazard with current
// reads), compute from buf, vmcnt(0)+barrier at bottom. The 4 in-flight DMAs
// span the compute phase instead of being drained before it. launch_bounds
// (256,2) — R4's regression is attributed to (256,3) regalloc pressure.
__global__ __launch_bounds__(256, 2)
void gemm_qkv(const f16* __restrict__ A, const f16* __restrict__ BT,
              const float* __restrict__ bias, f16* __restrict__ QKV)
{
    __shared__ __align__(16) f16 As[2][128 * 32];
    __shared__ __align__(16) f16 Bs[2][128 * 32];

    const int tid  = threadIdx.x;
    const int wave = tid >> 6;
    const int lane = tid & 63;
    const int quad = lane >> 4;
    const int l16  = lane & 15;
    const int wm   = (wave >> 1) * 64;
    const int wn   = (wave & 1) * 64;
    const int m0   = blockIdx.y * 128;
    const int n0   = blockIdx.x * 128;
    const int Ksz  = 1024;

    const int srow  = lane >> 2;
    const int skoff = (lane & 3) << 3;

    const f16* Ab = A  + (size_t)(m0 + wave * 16 + srow) * Ksz + skoff;
    const f16* Bb = BT + (size_t)(n0 + wave * 16 + srow) * Ksz + skoff;
    const size_t seg = (size_t)64 * Ksz;

    auto stage = [&](int buf, int kc) {
        f16* AsW = &As[buf][wave * 16 * 32];
        f16* BsW = &Bs[buf][wave * 16 * 32];
        async_copy16(AsW,           Ab + kc);
        async_copy16(AsW + 64 * 32, Ab + kc + seg);
        async_copy16(BsW,           Bb + kc);
        async_copy16(BsW + 64 * 32, Bb + kc + seg);
    };

    floatx4 acc[4][4] = {};

    stage(0, 0);
    asm volatile("s_waitcnt vmcnt(0)" ::: "memory");
    __syncthreads();

    int buf = 0;
    for (int kc = 0; kc < Ksz; kc += 32) {
        if (kc + 32 < Ksz) stage(buf ^ 1, kc + 32);   // prefetch into other buffer

        half8 a[4], b[4];
        #pragma unroll
        for (int mt = 0; mt < 4; ++mt)
            a[mt] = *(const half8*)&As[buf][(wm + mt * 16 + l16) * 32 + (quad << 3)];
        #pragma unroll
        for (int nt = 0; nt < 4; ++nt)
            b[nt] = *(const half8*)&Bs[buf][(wn + nt * 16 + l16) * 32 + (quad << 3)];
        #pragma unroll
        for (int mt = 0; mt < 4; ++mt)
            #pragma unroll
            for (int nt = 0; nt < 4; ++nt)
                acc[mt][nt] = mfma16(a[mt], b[nt], acc[mt][nt]);

        asm volatile("s_waitcnt vmcnt(0)" ::: "memory");   // prefetch landed
        __syncthreads();
        buf ^= 1;
    }

    const size_t HSZ = (size_t)32 * 2048 * 64;   // one of Q/K/V regions
    #pragma unroll
    for (int mt = 0; mt < 4; ++mt) {
        #pragma unroll
        for (int nt = 0; nt < 4; ++nt) {
            const int col  = n0 + wn + nt * 16 + l16;
            const float bv = bias[col];
            const int row0 = m0 + wm + mt * 16 + (quad << 2);
            const int bb   = row0 >> 11;
            const int t0   = row0 & 2047;
            const int hh   = (col >> 6) & 15;
            const int d    = col & 63;
            float v0 = acc[mt][nt][0] + bv;
            float v1 = acc[mt][nt][1] + bv;
            float v2 = acc[mt][nt][2] + bv;
            float v3 = acc[mt][nt][3] + bv;
            if (col < 2048) {   // Q or K: [bh][t][d]
                f16* dst = QKV + (size_t)(col >> 10) * HSZ
                         + (((size_t)(bb * 16 + hh) * 2048 + t0) << 6) + d;
                dst[0]   = (f16)v0;
                dst[64]  = (f16)v1;
                dst[128] = (f16)v2;
                dst[192] = (f16)v3;
            } else {            // V^T: [bh][d][t], 4 consecutive t -> half4
                half4 h; h[0]=(f16)v0; h[1]=(f16)v1; h[2]=(f16)v2; h[3]=(f16)v3;
                *(half4*)(QKV + 2 * HSZ
                          + (((size_t)(bb * 16 + hh) << 6) + d) * 2048 + t0) = h;
            }
        }
    }
}

// ---------------- proj GEMM: 128x64 tile (512 blocks = 2/CU, R2-exact) --------
__global__ __launch_bounds__(256, 2)
void gemm_proj(const f16* __restrict__ A, const f16* __restrict__ BT,
               const float* __restrict__ bias, float* __restrict__ C)
{
    __shared__ __align__(16) f16 As[128 * 32];
    __shared__ __align__(16) f16 Bs[64 * 32];

    const int tid  = threadIdx.x;
    const int wave = tid >> 6;
    const int lane = tid & 63;
    const int quad = lane >> 4;
    const int l16  = lane & 15;
    const int wm   = (wave >> 1) * 64;
    const int wn   = (wave & 1) * 32;
    const int m0   = blockIdx.y * 128;
    const int n0   = blockIdx.x * 64;
    const int Ksz  = 1024;

    const int srow  = lane >> 2;
    const int skoff = (lane & 3) << 3;

    const f16* Ab = A  + (size_t)(m0 + wave * 16 + srow) * Ksz + skoff;
    const f16* Bb = BT + (size_t)(n0 + wave * 16 + srow) * Ksz + skoff;
    f16* AsW = &As[wave * 16 * 32];
    f16* BsW = &Bs[wave * 16 * 32];
    const size_t seg = (size_t)64 * Ksz;

    floatx4 acc[4][2] = {};

    for (int kc = 0; kc < Ksz; kc += 32) {
        async_copy16(AsW,           Ab + kc);
        async_copy16(AsW + 64 * 32, Ab + kc + seg);
        async_copy16(BsW,           Bb + kc);
        asm volatile("s_waitcnt vmcnt(0)" ::: "memory");
        __syncthreads();

        half8 a[4], b[2];
        #pragma unroll
        for (int mt = 0; mt < 4; ++mt)
            a[mt] = *(const half8*)&As[(wm + mt * 16 + l16) * 32 + (quad << 3)];
        #pragma unroll
        for (int nt = 0; nt < 2; ++nt)
            b[nt] = *(const half8*)&Bs[(wn + nt * 16 + l16) * 32 + (quad << 3)];
        #pragma unroll
        for (int mt = 0; mt < 4; ++mt)
            #pragma unroll
            for (int nt = 0; nt < 2; ++nt)
                acc[mt][nt] = mfma16(a[mt], b[nt], acc[mt][nt]);
        __syncthreads();
    }

    #pragma unroll
    for (int mt = 0; mt < 4; ++mt) {
        #pragma unroll
        for (int nt = 0; nt < 2; ++nt) {
            const int col  = n0 + wn + nt * 16 + l16;
            const float bv = bias[col];
            #pragma unroll
            for (int r = 0; r < 4; ++r) {
                const int row = m0 + wm + mt * 16 + (quad << 2) + r;
                C[(size_t)row * 1024 + col] = acc[mt][nt][r] + bv;
            }
        }
    }
}

// ---------------- Flash attention, causal — FUSED DUAL-TILE COMPUTE (R8) ------
// time = chains x chain-cost; 34 dual chains/CU x ~3700cy = 52.4us (measured).
// compute2() processes BOTH q-tiles in ONE chain — interleaved QK MFMAs, exp for
// both, P-writes to two LDS buffers, ONE lgkmcnt(0), shared V fragments.
// Adjacent pairing (jA=2g, jB=2g+1); CU balance: blocks g and 15-g.
// bh-fastest grid (XCD-confined K/V), Vt 4-buf DMA 2 ahead, barrier per 2
// chunks, setprio around MFMA, swizzled V/P LDS.
__global__ __launch_bounds__(256, 2)
void attn_fwd(const f16* __restrict__ Qb, const f16* __restrict__ Kb,
              const f16* __restrict__ Vb, f16* __restrict__ attn_out)
{
    const int bh   = blockIdx.x;     // 0..31
    const int yy   = blockIdx.y;     // 0..15
    const int g    = (yy < 8) ? yy : 23 - yy;   // group 0..15; CU-pair g with 15-g
    const int jA   = 2 * g;          // even q-tile
    const int jB   = 2 * g + 1;      // odd q-tile (scan length)
    const int head = bh & 15;
    const int b    = bh >> 4;
    const int tid  = threadIdx.x;
    const int wave = tid >> 6;
    const int lane = tid & 63;
    const int quad = lane >> 4;
    const int l16  = lane & 15;

    __shared__ __align__(16) f16 Vt[4][64 * 64];   // [buf][d][kv], kv chunk8 ^ (d&7)
    __shared__ __align__(16) f16 PsB[4][16 * 64];  // per-wave P[q][kv] for tile B
    __shared__ __align__(16) f16 PsA[4][16 * 64];  // per-wave P[q][kv] for tile A

    const f16* Qh = Qb + ((size_t)bh << 17);
    const f16* Kh = Kb + ((size_t)bh << 17);
    const f16* Vh = Vb + ((size_t)bh << 17);

    // V DMA: wave stages d rows 16w..16w+15; instr g covers rows +8g..+8g+7.
    // lane L -> d-row r8=L>>3, source kv-chunk c8=(L&7)^r8 (XOR-swizzled LDS).
    const int r8 = lane >> 3;
    const int c8 = (lane & 7) ^ r8;
    const f16* vsrcA = Vh + (size_t)(wave * 16 + r8) * 2048 + c8 * 8;
    const f16* vsrcB = vsrcA + (size_t)8 * 2048;

    half8 kf[8], kn[8];
    half8 qA0, qA1, qB0, qB1;
    floatx4 oA[4], oB[4];
    float lpA, lpB;

    auto loadK = [&](int kv0, half8* dst) {
        const f16* kp = Kh + (size_t)(kv0 + l16) * 64 + (quad << 3);
        #pragma unroll
        for (int t = 0; t < 4; ++t) {
            dst[2 * t]     = *(const half8*)(kp + t * 16 * 64);
            dst[2 * t + 1] = *(const half8*)(kp + t * 16 * 64 + 32);
        }
    };
    auto dmaV = [&](int kv0, int buf) {
        async_copy16(&Vt[buf][(wave * 16) * 64],     vsrcA + kv0);
        async_copy16(&Vt[buf][(wave * 16 + 8) * 64], vsrcB + kv0);
    };

    const int sw = l16 & 7;   // swizzle key (= d&7 and q&7 for our rows)

    // BOTH q-tiles in one chain: interleaved QK, one lgkm wait, shared V frags.
    // Precondition: kc < jB (tile B never diagonal here); diagA = (kc == jA).
    auto compute2 = [&](int kc, bool diagA, half8* kcur) {
        floatx4 sB[4] = {};
        floatx4 sA[4] = {};
        __builtin_amdgcn_s_setprio(1);
        #pragma unroll
        for (int t = 0; t < 4; ++t) {
            sB[t] = mfma16(kcur[2 * t],     qB0, sB[t]);
            sA[t] = mfma16(kcur[2 * t],     qA0, sA[t]);
            sB[t] = mfma16(kcur[2 * t + 1], qB1, sB[t]);
            sA[t] = mfma16(kcur[2 * t + 1], qA1, sA[t]);
        }
        __builtin_amdgcn_s_setprio(0);
        const int qrel = (wave << 4) + l16;
        #pragma unroll
        for (int t = 0; t < 4; ++t) {
            const int c = t * 2 + (quad >> 1);
            const int po = (l16 << 6) + ((c ^ sw) << 3) + ((quad & 1) << 2);
            float b0 = __builtin_amdgcn_exp2f(sB[t][0]);
            float b1 = __builtin_amdgcn_exp2f(sB[t][1]);
            float b2 = __builtin_amdgcn_exp2f(sB[t][2]);
            float b3 = __builtin_amdgcn_exp2f(sB[t][3]);
            lpB += (b0 + b1) + (b2 + b3);
            half4 pkB; pkB[0]=(f16)b0; pkB[1]=(f16)b1; pkB[2]=(f16)b2; pkB[3]=(f16)b3;
            *(half4*)&PsB[wave][po] = pkB;
            float a0 = __builtin_amdgcn_exp2f(sA[t][0]);
            float a1 = __builtin_amdgcn_exp2f(sA[t][1]);
            float a2 = __builtin_amdgcn_exp2f(sA[t][2]);
            float a3 = __builtin_amdgcn_exp2f(sA[t][3]);
            if (diagA) {
                const int kvb = t * 16 + (quad << 2);
                a0 = (kvb     <= qrel) ? a0 : 0.f;
                a1 = (kvb + 1 <= qrel) ? a1 : 0.f;
                a2 = (kvb + 2 <= qrel) ? a2 : 0.f;
                a3 = (kvb + 3 <= qrel) ? a3 : 0.f;
            }
            lpA += (a0 + a1) + (a2 + a3);
            half4 pkA; pkA[0]=(f16)a0; pkA[1]=(f16)a1; pkA[2]=(f16)a2; pkA[3]=(f16)a3;
            *(half4*)&PsA[wave][po] = pkA;
        }
        asm volatile("s_waitcnt lgkmcnt(0)" ::: "memory");
        half8 pB0 = *(const half8*)&PsB[wave][(l16 << 6) + (((quad    ) ^ sw) << 3)];
        half8 pB1 = *(const half8*)&PsB[wave][(l16 << 6) + (((quad + 4) ^ sw) << 3)];
        half8 pA0 = *(const half8*)&PsA[wave][(l16 << 6) + (((quad    ) ^ sw) << 3)];
        half8 pA1 = *(const half8*)&PsA[wave][(l16 << 6) + (((quad + 4) ^ sw) << 3)];
        const f16* vbuf = &Vt[kc & 3][0];
        __builtin_amdgcn_s_setprio(1);
        #pragma unroll
        for (int dt = 0; dt < 4; ++dt) {
            const f16* vrow = vbuf + ((dt * 16 + l16) << 6);
            half8 vf0 = *(const half8*)(vrow + (((quad    ) ^ sw) << 3));
            half8 vf1 = *(const half8*)(vrow + (((quad + 4) ^ sw) << 3));
            oB[dt] = mfma16(pB0, vf0, oB[dt]);
            oA[dt] = mfma16(pA0, vf0, oA[dt]);
            oB[dt] = mfma16(pB1, vf1, oB[dt]);
            oA[dt] = mfma16(pA1, vf1, oA[dt]);
        }
        __builtin_amdgcn_s_setprio(0);
    };

    // single-tile chunk (B-only tail), diag = (kc == jB)
    auto compute1 = [&](int kc, half8* kcur) {
        floatx4 s[4] = {};
        __builtin_amdgcn_s_setprio(1);
        #pragma unroll
        for (int t = 0; t < 4; ++t) {
            s[t] = mfma16(kcur[2 * t],     qB0, s[t]);
            s[t] = mfma16(kcur[2 * t + 1], qB1, s[t]);
        }
        __builtin_amdgcn_s_setprio(0);
        const bool diag = (kc == jB);
        const int qrel = (wave << 4) + l16;
        #pragma unroll
        for (int t = 0; t < 4; ++t) {
            float p0 = __builtin_amdgcn_exp2f(s[t][0]);
            float p1 = __builtin_amdgcn_exp2f(s[t][1]);
            float p2 = __builtin_amdgcn_exp2f(s[t][2]);
            float p3 = __builtin_amdgcn_exp2f(s[t][3]);
            if (diag) {
                const int kvb = t * 16 + (quad << 2);
                p0 = (kvb     <= qrel) ? p0 : 0.f;
                p1 = (kvb + 1 <= qrel) ? p1 : 0.f;
                p2 = (kvb + 2 <= qrel) ? p2 : 0.f;
                p3 = (kvb + 3 <= qrel) ? p3 : 0.f;
            }
            lpB += (p0 + p1) + (p2 + p3);
            half4 pk; pk[0]=(f16)p0; pk[1]=(f16)p1; pk[2]=(f16)p2; pk[3]=(f16)p3;
            const int c = t * 2 + (quad >> 1);
            *(half4*)&PsB[wave][(l16 << 6) + ((c ^ sw) << 3) + ((quad & 1) << 2)] = pk;
        }
        asm volatile("s_waitcnt lgkmcnt(0)" ::: "memory");
        half8 pf0 = *(const half8*)&PsB[wave][(l16 << 6) + (((quad    ) ^ sw) << 3)];
        half8 pf1 = *(const half8*)&PsB[wave][(l16 << 6) + (((quad + 4) ^ sw) << 3)];
        const f16* vbuf = &Vt[kc & 3][0];
        __builtin_amdgcn_s_setprio(1);
        #pragma unroll
        for (int dt = 0; dt < 4; ++dt) {
            const f16* vrow = vbuf + ((dt * 16 + l16) << 6);
            half8 vf0 = *(const half8*)(vrow + (((quad    ) ^ sw) << 3));
            half8 vf1 = *(const half8*)(vrow + (((quad + 4) ^ sw) << 3));
            oB[dt] = mfma16(pf0, vf0, oB[dt]);
            oB[dt] = mfma16(pf1, vf1, oB[dt]);
        }
        __builtin_amdgcn_s_setprio(0);
    };

    const f16 qs = (f16)0.1803368801f;   // (1/8) * log2(e)
    auto loadQ = [&](int j, half8& q0, half8& q1) {
        const f16* qp = Qh + (size_t)(j * 64 + wave * 16 + l16) * 64 + (quad << 3);
        q0 = *(const half8*)qp;
        q1 = *(const half8*)(qp + 32);
        #pragma unroll
        for (int i = 0; i < 8; ++i) { q0[i] *= qs; q1[i] *= qs; }
    };

    loadQ(jA, qA0, qA1);
    loadQ(jB, qB0, qB1);
    oA[0]=oA[1]=oA[2]=oA[3] = (floatx4){0.f,0.f,0.f,0.f};
    oB[0]=oB[1]=oB[2]=oB[3] = (floatx4){0.f,0.f,0.f,0.f};
    lpA = 0.f; lpB = 0.f;

    const int nB = jB + 1;   // = 2g+2 >= 2, always even
    loadK(0, kf);
    dmaV(0, 0);
    dmaV(64, 1);

    // pair loop: one barrier per TWO chunks; DMA chunks kc+2/kc+3 at pair top.
    // Even kc <= jA always -> compute2 (diagA iff kc==jA). Odd kc+1: compute2
    // while kc+1 <= jA (never diagonal, parity), else compute1 (B diag tail).
    for (int kc = 0; kc < nB; kc += 2) {
        __syncthreads();
        if (kc + 2 < nB) dmaV((kc + 2) << 6, (kc + 2) & 3);
        if (kc + 3 < nB) dmaV((kc + 3) << 6, (kc + 3) & 3);
        if (kc + 1 < nB) loadK((kc + 1) << 6, kn);
        compute2(kc, kc == jA, kf);
        if (kc + 1 < nB) {
            if (kc + 2 < nB) loadK((kc + 2) << 6, kf);
            if (kc + 1 <= jA) compute2(kc + 1, false, kn);
            else               compute1(kc + 1, kn);
        }
    }

    // epilogue per q-tile: reduce l over quads, transpose inv via shuffles, write O
    auto writeO = [&](int j, floatx4* o, float lp) {
        float l = lp;
        l += __shfl_xor(l, 16);
        l += __shfl_xor(l, 32);
        const float inv = 1.f / l;
        const int qrow0 = j * 64 + wave * 16;
        #pragma unroll
        for (int r = 0; r < 4; ++r) {
            const float invr = __shfl(inv, (quad << 2) + r);
            const int row = (b << 11) + qrow0 + (quad << 2) + r;
            f16* op = attn_out + (size_t)row * 1024 + head * 64 + l16;
            #pragma unroll
            for (int dt = 0; dt < 4; ++dt)
                op[dt * 16] = (f16)(o[dt][r] * invr);
        }
    };
    writeO(jB, oB, lpB);
    writeO(jA, oA, lpA);
}

extern "C" void kernel_launch(void* const* d_in, const int* in_sizes, int n_in,
                              void* d_out, int out_size, void* d_ws, size_t ws_size,
                              hipStream_t stream)
{
    const float* x      = (const float*)d_in[0];
    const float* w_attn = (const float*)d_in[1];
    const float* b_attn = (const float*)d_in[2];
    const float* w_proj = (const float*)d_in[3];
    const float* b_proj = (const float*)d_in[4];
    float* y = (float*)d_out;

    f16* xh       = (f16*)d_ws;                         // [4096,1024]
    f16* wattnT   = xh + (size_t)4096 * 1024;           // [3072,1024]
    f16* wprojT   = wattnT + (size_t)3072 * 1024;       // [1024,1024]
    f16* qkv      = wprojT + (size_t)1024 * 1024;       // Q,K: [32][2048][64]; V: [32][64][2048]
    f16* attn_out = qkv + (size_t)3 * 32 * 2048 * 64;   // [4096,1024]

    const size_t HSZ = (size_t)32 * 2048 * 64;

    prepass<<<dim3(3072), dim3(256), 0, stream>>>(x, w_attn, w_proj, xh, wattnT, wprojT);
    gemm_qkv<<<dim3(24, 32), dim3(256), 0, stream>>>(xh, wattnT, b_attn, qkv);
    attn_fwd<<<dim3(32, 16), dim3(256), 0, stream>>>(qkv, qkv + HSZ, qkv + 2 * HSZ, attn_out);
    gemm_proj<<<dim3(16, 32), dim3(256), 0, stream>>>(attn_out, wprojT, b_proj, y);
}

// Round 11
// 189.357 us; speedup vs baseline: 1.0800x; 1.0055x over previous
//
#include <hip/hip_runtime.h>
#include <stdint.h>
#include <stddef.h>

typedef _Float16 f16;
typedef _Float16 half8 __attribute__((ext_vector_type(8)));
typedef _Float16 half4 __attribute__((ext_vector_type(4)));
typedef float floatx4 __attribute__((ext_vector_type(4)));

__device__ __forceinline__ floatx4 mfma16(half8 a, half8 b, floatx4 c) {
    return __builtin_amdgcn_mfma_f32_16x16x32_f16(a, b, c, 0, 0, 0);
}

typedef __attribute__((address_space(3))) void       lds_void_t;
typedef const __attribute__((address_space(1))) void gconst_void_t;

// async 16B/lane global->LDS; lds dest = wave-uniform base + lane*16
__device__ __forceinline__ void async_copy16(void* lds, const void* g) {
    __builtin_amdgcn_global_load_lds((gconst_void_t*)g, (lds_void_t*)lds, 16, 0, 0);
}

// ---------------- fused pre-pass ----------------
// blocks [0,2048): convert x f32->f16 row-major
// blocks [2048,2816): transpose w_attn [1024,3072] -> wattnT [3072,1024] f16
// blocks [2816,3072): transpose w_proj [1024,1024] -> wprojT [1024,1024] f16
__global__ __launch_bounds__(256)
void prepass(const float* __restrict__ x, const float* __restrict__ w_attn,
             const float* __restrict__ w_proj,
             f16* __restrict__ xh, f16* __restrict__ wattnT, f16* __restrict__ wprojT)
{
    __shared__ __align__(16) f16 t[64][72];
    const int bid = blockIdx.x;
    if (bid < 2048) {
        const size_t i = ((size_t)bid * 256 + threadIdx.x) * 8;
        floatx4 a = *(const floatx4*)(x + i);
        floatx4 b = *(const floatx4*)(x + i + 4);
        half8 h;
        h[0]=(f16)a[0]; h[1]=(f16)a[1]; h[2]=(f16)a[2]; h[3]=(f16)a[3];
        h[4]=(f16)b[0]; h[5]=(f16)b[1]; h[6]=(f16)b[2]; h[7]=(f16)b[3];
        *(half8*)(xh + i) = h;
        return;
    }
    const float* W; f16* WT; int Nsz, bx, by;
    if (bid < 2816) {
        W = w_attn; WT = wattnT; Nsz = 3072;
        const int r = bid - 2048; by = r / 48; bx = r - by * 48;
    } else {
        W = w_proj; WT = wprojT; Nsz = 1024;
        const int r = bid - 2816; by = r >> 4; bx = r & 15;
    }
    const int k0 = by << 6;
    const int n0 = bx << 6;
    {
        const int r  = threadIdx.x >> 2;
        const int c0 = (threadIdx.x & 3) << 4;
        #pragma unroll
        for (int i = 0; i < 4; ++i) {
            const int c = c0 + (i << 2);
            floatx4 v = *(const floatx4*)(W + (size_t)(k0 + r) * Nsz + n0 + c);
            t[c + 0][r] = (f16)v[0];
            t[c + 1][r] = (f16)v[1];
            t[c + 2][r] = (f16)v[2];
            t[c + 3][r] = (f16)v[3];
        }
    }
    __syncthreads();
    {
        const int n  = threadIdx.x >> 2;
        const int kc = (threadIdx.x & 3) << 4;
        #pragma unroll
        for (int i = 0; i < 2; ++i) {
            half8 h = *(half8*)&t[n][kc + (i << 3)];
            *(half8*)(WT + (size_t)(n0 + n) * 1024 + k0 + kc + (i << 3)) = h;
        }
    }
}

// ---------------- QKV GEMM ----------------
// R11: TRUE T3+T4 loop — counted vmcnt + RAW s_barrier (no __syncthreads, so
// no compiler-inserted vmcnt(0) drain; R10's neutral result is explained by
// that implicit drain nullifying the prefetch). Per iter:
//   stage(buf^1) ; vmcnt(4)  [prev 4 landed, new 4 stay IN FLIGHT all iter]
//   s_barrier    [buf's DMA visible to all waves]
//   ds_read buf ; lgkmcnt(0)+sched_barrier (rule #18)
//   s_barrier    [all waves' reads retired -> buf free for next iter's DMA]
//   MFMA (register-only; safe to schedule after barrier)
// Tail iter waits vmcnt(0). Epilogue: R2-coalesced stores (R9 proved swapped
// epilogues hurt).
__global__ __launch_bounds__(256, 2)
void gemm_qkv(const f16* __restrict__ A, const f16* __restrict__ BT,
              const float* __restrict__ bias, f16* __restrict__ QKV)
{
    __shared__ __align__(16) f16 As[2][128 * 32];
    __shared__ __align__(16) f16 Bs[2][128 * 32];

    const int tid  = threadIdx.x;
    const int wave = tid >> 6;
    const int lane = tid & 63;
    const int quad = lane >> 4;
    const int l16  = lane & 15;
    const int wm   = (wave >> 1) * 64;
    const int wn   = (wave & 1) * 64;
    const int m0   = blockIdx.y * 128;
    const int n0   = blockIdx.x * 128;
    const int Ksz  = 1024;

    const int srow  = lane >> 2;
    const int skoff = (lane & 3) << 3;

    const f16* Ab = A  + (size_t)(m0 + wave * 16 + srow) * Ksz + skoff;
    const f16* Bb = BT + (size_t)(n0 + wave * 16 + srow) * Ksz + skoff;
    const size_t seg = (size_t)64 * Ksz;

    auto stage = [&](int buf, int kc) {
        f16* AsW = &As[buf][wave * 16 * 32];
        f16* BsW = &Bs[buf][wave * 16 * 32];
        async_copy16(AsW,           Ab + kc);
        async_copy16(AsW + 64 * 32, Ab + kc + seg);
        async_copy16(BsW,           Bb + kc);
        async_copy16(BsW + 64 * 32, Bb + kc + seg);
    };

    floatx4 acc[4][4] = {};

    stage(0, 0);   // 4 loads in flight

    int buf = 0;
    for (int kc = 0; kc < Ksz; kc += 32) {
        if (kc + 32 < Ksz) {
            stage(buf ^ 1, kc + 32);                       // 8 in flight
            asm volatile("s_waitcnt vmcnt(4)" ::: "memory");  // prev 4 landed
        } else {
            asm volatile("s_waitcnt vmcnt(0)" ::: "memory");
        }
        __builtin_amdgcn_sched_barrier(0);
        __builtin_amdgcn_s_barrier();          // buf readable by all waves
        __builtin_amdgcn_sched_barrier(0);

        half8 a[4], b[4];
        #pragma unroll
        for (int mt = 0; mt < 4; ++mt)
            a[mt] = *(const half8*)&As[buf][(wm + mt * 16 + l16) * 32 + (quad << 3)];
        #pragma unroll
        for (int nt = 0; nt < 4; ++nt)
            b[nt] = *(const half8*)&Bs[buf][(wn + nt * 16 + l16) * 32 + (quad << 3)];
        asm volatile("s_waitcnt lgkmcnt(0)" ::: "memory");   // reads retired
        __builtin_amdgcn_sched_barrier(0);
        __builtin_amdgcn_s_barrier();          // buf free for next iter's DMA

        #pragma unroll
        for (int mt = 0; mt < 4; ++mt)
            #pragma unroll
            for (int nt = 0; nt < 4; ++nt)
                acc[mt][nt] = mfma16(a[mt], b[nt], acc[mt][nt]);
        buf ^= 1;
    }

    const size_t HSZ = (size_t)32 * 2048 * 64;   // one of Q/K/V regions
    #pragma unroll
    for (int mt = 0; mt < 4; ++mt) {
        #pragma unroll
        for (int nt = 0; nt < 4; ++nt) {
            const int col  = n0 + wn + nt * 16 + l16;
            const float bv = bias[col];
            const int row0 = m0 + wm + mt * 16 + (quad << 2);
            const int bb   = row0 >> 11;
            const int t0   = row0 & 2047;
            const int hh   = (col >> 6) & 15;
            const int d    = col & 63;
            float v0 = acc[mt][nt][0] + bv;
            float v1 = acc[mt][nt][1] + bv;
            float v2 = acc[mt][nt][2] + bv;
            float v3 = acc[mt][nt][3] + bv;
            if (col < 2048) {   // Q or K: [bh][t][d]
                f16* dst = QKV + (size_t)(col >> 10) * HSZ
                         + (((size_t)(bb * 16 + hh) * 2048 + t0) << 6) + d;
                dst[0]   = (f16)v0;
                dst[64]  = (f16)v1;
                dst[128] = (f16)v2;
                dst[192] = (f16)v3;
            } else {            // V^T: [bh][d][t], 4 consecutive t -> half4
                half4 h; h[0]=(f16)v0; h[1]=(f16)v1; h[2]=(f16)v2; h[3]=(f16)v3;
                *(half4*)(QKV + 2 * HSZ
                          + (((size_t)(bb * 16 + hh) << 6) + d) * 2048 + t0) = h;
            }
        }
    }
}

// ---------------- proj GEMM: 128x64 tile (512 blocks = 2/CU) ----------------
// R11: same counted-vmcnt + raw-barrier loop (3 loads/stage -> vmcnt(3)).
__global__ __launch_bounds__(256, 2)
void gemm_proj(const f16* __restrict__ A, const f16* __restrict__ BT,
               const float* __restrict__ bias, float* __restrict__ C)
{
    __shared__ __align__(16) f16 As[2][128 * 32];
    __shared__ __align__(16) f16 Bs[2][64 * 32];

    const int tid  = threadIdx.x;
    const int wave = tid >> 6;
    const int lane = tid & 63;
    const int quad = lane >> 4;
    const int l16  = lane & 15;
    const int wm   = (wave >> 1) * 64;
    const int wn   = (wave & 1) * 32;
    const int m0   = blockIdx.y * 128;
    const int n0   = blockIdx.x * 64;
    const int Ksz  = 1024;

    const int srow  = lane >> 2;
    const int skoff = (lane & 3) << 3;

    const f16* Ab = A  + (size_t)(m0 + wave * 16 + srow) * Ksz + skoff;
    const f16* Bb = BT + (size_t)(n0 + wave * 16 + srow) * Ksz + skoff;
    const size_t seg = (size_t)64 * Ksz;

    auto stage = [&](int buf, int kc) {
        f16* AsW = &As[buf][wave * 16 * 32];
        f16* BsW = &Bs[buf][wave * 16 * 32];
        async_copy16(AsW,           Ab + kc);
        async_copy16(AsW + 64 * 32, Ab + kc + seg);
        async_copy16(BsW,           Bb + kc);
    };

    floatx4 acc[4][2] = {};

    stage(0, 0);

    int buf = 0;
    for (int kc = 0; kc < Ksz; kc += 32) {
        if (kc + 32 < Ksz) {
            stage(buf ^ 1, kc + 32);
            asm volatile("s_waitcnt vmcnt(3)" ::: "memory");
        } else {
            asm volatile("s_waitcnt vmcnt(0)" ::: "memory");
        }
        __builtin_amdgcn_sched_barrier(0);
        __builtin_amdgcn_s_barrier();
        __builtin_amdgcn_sched_barrier(0);

        half8 a[4], b[2];
        #pragma unroll
        for (int mt = 0; mt < 4; ++mt)
            a[mt] = *(const half8*)&As[buf][(wm + mt * 16 + l16) * 32 + (quad << 3)];
        #pragma unroll
        for (int nt = 0; nt < 2; ++nt)
            b[nt] = *(const half8*)&Bs[buf][(wn + nt * 16 + l16) * 32 + (quad << 3)];
        asm volatile("s_waitcnt lgkmcnt(0)" ::: "memory");
        __builtin_amdgcn_sched_barrier(0);
        __builtin_amdgcn_s_barrier();

        #pragma unroll
        for (int mt = 0; mt < 4; ++mt)
            #pragma unroll
            for (int nt = 0; nt < 2; ++nt)
                acc[mt][nt] = mfma16(a[mt], b[nt], acc[mt][nt]);
        buf ^= 1;
    }

    #pragma unroll
    for (int mt = 0; mt < 4; ++mt) {
        #pragma unroll
        for (int nt = 0; nt < 2; ++nt) {
            const int col  = n0 + wn + nt * 16 + l16;
            const float bv = bias[col];
            #pragma unroll
            for (int r = 0; r < 4; ++r) {
                const int row = m0 + wm + mt * 16 + (quad << 2) + r;
                C[(size_t)row * 1024 + col] = acc[mt][nt][r] + bv;
            }
        }
    }
}

// ---------------- Flash attention, causal — FUSED DUAL-TILE COMPUTE (R8) ------
// time = chains x chain-cost; 34 dual chains/CU x ~3700cy = 52.4us (measured).
// compute2() processes BOTH q-tiles in ONE chain — interleaved QK MFMAs, exp for
// both, P-writes to two LDS buffers, ONE lgkmcnt(0), shared V fragments.
// Adjacent pairing (jA=2g, jB=2g+1); CU balance: blocks g and 15-g.
// bh-fastest grid (XCD-confined K/V), Vt 4-buf DMA 2 ahead, barrier per 2
// chunks, setprio around MFMA, swizzled V/P LDS.
__global__ __launch_bounds__(256, 2)
void attn_fwd(const f16* __restrict__ Qb, const f16* __restrict__ Kb,
              const f16* __restrict__ Vb, f16* __restrict__ attn_out)
{
    const int bh   = blockIdx.x;     // 0..31
    const int yy   = blockIdx.y;     // 0..15
    const int g    = (yy < 8) ? yy : 23 - yy;   // group 0..15; CU-pair g with 15-g
    const int jA   = 2 * g;          // even q-tile
    const int jB   = 2 * g + 1;      // odd q-tile (scan length)
    const int head = bh & 15;
    const int b    = bh >> 4;
    const int tid  = threadIdx.x;
    const int wave = tid >> 6;
    const int lane = tid & 63;
    const int quad = lane >> 4;
    const int l16  = lane & 15;

    __shared__ __align__(16) f16 Vt[4][64 * 64];   // [buf][d][kv], kv chunk8 ^ (d&7)
    __shared__ __align__(16) f16 PsB[4][16 * 64];  // per-wave P[q][kv] for tile B
    __shared__ __align__(16) f16 PsA[4][16 * 64];  // per-wave P[q][kv] for tile A

    const f16* Qh = Qb + ((size_t)bh << 17);
    const f16* Kh = Kb + ((size_t)bh << 17);
    const f16* Vh = Vb + ((size_t)bh << 17);

    // V DMA: wave stages d rows 16w..16w+15; instr g covers rows +8g..+8g+7.
    // lane L -> d-row r8=L>>3, source kv-chunk c8=(L&7)^r8 (XOR-swizzled LDS).
    const int r8 = lane >> 3;
    const int c8 = (lane & 7) ^ r8;
    const f16* vsrcA = Vh + (size_t)(wave * 16 + r8) * 2048 + c8 * 8;
    const f16* vsrcB = vsrcA + (size_t)8 * 2048;

    half8 kf[8], kn[8];
    half8 qA0, qA1, qB0, qB1;
    floatx4 oA[4], oB[4];
    float lpA, lpB;

    auto loadK = [&](int kv0, half8* dst) {
        const f16* kp = Kh + (size_t)(kv0 + l16) * 64 + (quad << 3);
        #pragma unroll
        for (int t = 0; t < 4; ++t) {
            dst[2 * t]     = *(const half8*)(kp + t * 16 * 64);
            dst[2 * t + 1] = *(const half8*)(kp + t * 16 * 64 + 32);
        }
    };
    auto dmaV = [&](int kv0, int buf) {
        async_copy16(&Vt[buf][(wave * 16) * 64],     vsrcA + kv0);
        async_copy16(&Vt[buf][(wave * 16 + 8) * 64], vsrcB + kv0);
    };

    const int sw = l16 & 7;   // swizzle key (= d&7 and q&7 for our rows)

    // BOTH q-tiles in one chain: interleaved QK, one lgkm wait, shared V frags.
    // Precondition: kc < jB (tile B never diagonal here); diagA = (kc == jA).
    auto compute2 = [&](int kc, bool diagA, half8* kcur) {
        floatx4 sB[4] = {};
        floatx4 sA[4] = {};
        __builtin_amdgcn_s_setprio(1);
        #pragma unroll
        for (int t = 0; t < 4; ++t) {
            sB[t] = mfma16(kcur[2 * t],     qB0, sB[t]);
            sA[t] = mfma16(kcur[2 * t],     qA0, sA[t]);
            sB[t] = mfma16(kcur[2 * t + 1], qB1, sB[t]);
            sA[t] = mfma16(kcur[2 * t + 1], qA1, sA[t]);
        }
        __builtin_amdgcn_s_setprio(0);
        const int qrel = (wave << 4) + l16;
        #pragma unroll
        for (int t = 0; t < 4; ++t) {
            const int c = t * 2 + (quad >> 1);
            const int po = (l16 << 6) + ((c ^ sw) << 3) + ((quad & 1) << 2);
            float b0 = __builtin_amdgcn_exp2f(sB[t][0]);
            float b1 = __builtin_amdgcn_exp2f(sB[t][1]);
            float b2 = __builtin_amdgcn_exp2f(sB[t][2]);
            float b3 = __builtin_amdgcn_exp2f(sB[t][3]);
            lpB += (b0 + b1) + (b2 + b3);
            half4 pkB; pkB[0]=(f16)b0; pkB[1]=(f16)b1; pkB[2]=(f16)b2; pkB[3]=(f16)b3;
            *(half4*)&PsB[wave][po] = pkB;
            float a0 = __builtin_amdgcn_exp2f(sA[t][0]);
            float a1 = __builtin_amdgcn_exp2f(sA[t][1]);
            float a2 = __builtin_amdgcn_exp2f(sA[t][2]);
            float a3 = __builtin_amdgcn_exp2f(sA[t][3]);
            if (diagA) {
                const int kvb = t * 16 + (quad << 2);
                a0 = (kvb     <= qrel) ? a0 : 0.f;
                a1 = (kvb + 1 <= qrel) ? a1 : 0.f;
                a2 = (kvb + 2 <= qrel) ? a2 : 0.f;
                a3 = (kvb + 3 <= qrel) ? a3 : 0.f;
            }
            lpA += (a0 + a1) + (a2 + a3);
            half4 pkA; pkA[0]=(f16)a0; pkA[1]=(f16)a1; pkA[2]=(f16)a2; pkA[3]=(f16)a3;
            *(half4*)&PsA[wave][po] = pkA;
        }
        asm volatile("s_waitcnt lgkmcnt(0)" ::: "memory");
        half8 pB0 = *(const half8*)&PsB[wave][(l16 << 6) + (((quad    ) ^ sw) << 3)];
        half8 pB1 = *(const half8*)&PsB[wave][(l16 << 6) + (((quad + 4) ^ sw) << 3)];
        half8 pA0 = *(const half8*)&PsA[wave][(l16 << 6) + (((quad    ) ^ sw) << 3)];
        half8 pA1 = *(const half8*)&PsA[wave][(l16 << 6) + (((quad + 4) ^ sw) << 3)];
        const f16* vbuf = &Vt[kc & 3][0];
        __builtin_amdgcn_s_setprio(1);
        #pragma unroll
        for (int dt = 0; dt < 4; ++dt) {
            const f16* vrow = vbuf + ((dt * 16 + l16) << 6);
            half8 vf0 = *(const half8*)(vrow + (((quad    ) ^ sw) << 3));
            half8 vf1 = *(const half8*)(vrow + (((quad + 4) ^ sw) << 3));
            oB[dt] = mfma16(pB0, vf0, oB[dt]);
            oA[dt] = mfma16(pA0, vf0, oA[dt]);
            oB[dt] = mfma16(pB1, vf1, oB[dt]);
            oA[dt] = mfma16(pA1, vf1, oA[dt]);
        }
        __builtin_amdgcn_s_setprio(0);
    };

    // single-tile chunk (B-only tail), diag = (kc == jB)
    auto compute1 = [&](int kc, half8* kcur) {
        floatx4 s[4] = {};
        __builtin_amdgcn_s_setprio(1);
        #pragma unroll
        for (int t = 0; t < 4; ++t) {
            s[t] = mfma16(kcur[2 * t],     qB0, s[t]);
            s[t] = mfma16(kcur[2 * t + 1], qB1, s[t]);
        }
        __builtin_amdgcn_s_setprio(0);
        const bool diag = (kc == jB);
        const int qrel = (wave << 4) + l16;
        #pragma unroll
        for (int t = 0; t < 4; ++t) {
            float p0 = __builtin_amdgcn_exp2f(s[t][0]);
            float p1 = __builtin_amdgcn_exp2f(s[t][1]);
            float p2 = __builtin_amdgcn_exp2f(s[t][2]);
            float p3 = __builtin_amdgcn_exp2f(s[t][3]);
            if (diag) {
                const int kvb = t * 16 + (quad << 2);
                p0 = (kvb     <= qrel) ? p0 : 0.f;
                p1 = (kvb + 1 <= qrel) ? p1 : 0.f;
                p2 = (kvb + 2 <= qrel) ? p2 : 0.f;
                p3 = (kvb + 3 <= qrel) ? p3 : 0.f;
            }
            lpB += (p0 + p1) + (p2 + p3);
            half4 pk; pk[0]=(f16)p0; pk[1]=(f16)p1; pk[2]=(f16)p2; pk[3]=(f16)p3;
            const int c = t * 2 + (quad >> 1);
            *(half4*)&PsB[wave][(l16 << 6) + ((c ^ sw) << 3) + ((quad & 1) << 2)] = pk;
        }
        asm volatile("s_waitcnt lgkmcnt(0)" ::: "memory");
        half8 pf0 = *(const half8*)&PsB[wave][(l16 << 6) + (((quad    ) ^ sw) << 3)];
        half8 pf1 = *(const half8*)&PsB[wave][(l16 << 6) + (((quad + 4) ^ sw) << 3)];
        const f16* vbuf = &Vt[kc & 3][0];
        __builtin_amdgcn_s_setprio(1);
        #pragma unroll
        for (int dt = 0; dt < 4; ++dt) {
            const f16* vrow = vbuf + ((dt * 16 + l16) << 6);
            half8 vf0 = *(const half8*)(vrow + (((quad    ) ^ sw) << 3));
            half8 vf1 = *(const half8*)(vrow + (((quad + 4) ^ sw) << 3));
            oB[dt] = mfma16(pf0, vf0, oB[dt]);
            oB[dt] = mfma16(pf1, vf1, oB[dt]);
        }
        __builtin_amdgcn_s_setprio(0);
    };

    const f16 qs = (f16)0.1803368801f;   // (1/8) * log2(e)
    auto loadQ = [&](int j, half8& q0, half8& q1) {
        const f16* qp = Qh + (size_t)(j * 64 + wave * 16 + l16) * 64 + (quad << 3);
        q0 = *(const half8*)qp;
        q1 = *(const half8*)(qp + 32);
        #pragma unroll
        for (int i = 0; i < 8; ++i) { q0[i] *= qs; q1[i] *= qs; }
    };

    loadQ(jA, qA0, qA1);
    loadQ(jB, qB0, qB1);
    oA[0]=oA[1]=oA[2]=oA[3] = (floatx4){0.f,0.f,0.f,0.f};
    oB[0]=oB[1]=oB[2]=oB[3] = (floatx4){0.f,0.f,0.f,0.f};
    lpA = 0.f; lpB = 0.f;

    const int nB = jB + 1;   // = 2g+2 >= 2, always even
    loadK(0, kf);
    dmaV(0, 0);
    dmaV(64, 1);

    // pair loop: one barrier per TWO chunks; DMA chunks kc+2/kc+3 at pair top.
    // Even kc <= jA always -> compute2 (diagA iff kc==jA). Odd kc+1: compute2
    // while kc+1 <= jA (never diagonal, parity), else compute1 (B diag tail).
    for (int kc = 0; kc < nB; kc += 2) {
        __syncthreads();
        if (kc + 2 < nB) dmaV((kc + 2) << 6, (kc + 2) & 3);
        if (kc + 3 < nB) dmaV((kc + 3) << 6, (kc + 3) & 3);
        if (kc + 1 < nB) loadK((kc + 1) << 6, kn);
        compute2(kc, kc == jA, kf);
        if (kc + 1 < nB) {
            if (kc + 2 < nB) loadK((kc + 2) << 6, kf);
            if (kc + 1 <= jA) compute2(kc + 1, false, kn);
            else               compute1(kc + 1, kn);
        }
    }

    // epilogue per q-tile: reduce l over quads, transpose inv via shuffles, write O
    auto writeO = [&](int j, floatx4* o, float lp) {
        float l = lp;
        l += __shfl_xor(l, 16);
        l += __shfl_xor(l, 32);
        const float inv = 1.f / l;
        const int qrow0 = j * 64 + wave * 16;
        #pragma unroll
        for (int r = 0; r < 4; ++r) {
            const float invr = __shfl(inv, (quad << 2) + r);
            const int row = (b << 11) + qrow0 + (quad << 2) + r;
            f16* op = attn_out + (size_t)row * 1024 + head * 64 + l16;
            #pragma unroll
            for (int dt = 0; dt < 4; ++dt)
                op[dt * 16] = (f16)(o[dt][r] * invr);
        }
    };
    writeO(jB, oB, lpB);
    writeO(jA, oA, lpA);
}

extern "C" void kernel_launch(void* const* d_in, const int* in_sizes, int n_in,
                              void* d_out, int out_size, void* d_ws, size_t ws_size,
                              hipStream_t stream)
{
    const float* x      = (const float*)d_in[0];
    const float* w_attn = (const float*)d_in[1];
    const float* b_attn = (const float*)d_in[2];
    const float* w_proj = (const float*)d_in[3];
    const float* b_proj = (const float*)d_in[4];
    float* y = (float*)d_out;

    f16* xh       = (f16*)d_ws;                         // [4096,1024]
    f16* wattnT   = xh + (size_t)4096 * 1024;           // [3072,1024]
    f16* wprojT   = wattnT + (size_t)3072 * 1024;       // [1024,1024]
    f16* qkv      = wprojT + (size_t)1024 * 1024;       // Q,K: [32][2048][64]; V: [32][64][2048]
    f16* attn_out = qkv + (size_t)3 * 32 * 2048 * 64;   // [4096,1024]

    const size_t HSZ = (size_t)32 * 2048 * 64;

    prepass<<<dim3(3072), dim3(256), 0, stream>>>(x, w_attn, w_proj, xh, wattnT, wprojT);
    gemm_qkv<<<dim3(24, 32), dim3(256), 0, stream>>>(xh, wattnT, b_attn, qkv);
    attn_fwd<<<dim3(32, 16), dim3(256), 0, stream>>>(qkv, qkv + HSZ, qkv + 2 * HSZ, attn_out);
    gemm_proj<<<dim3(16, 32), dim3(256), 0, stream>>>(attn_out, wprojT, b_proj, y);
}

// Round 12
// 185.543 us; speedup vs baseline: 1.1022x; 1.0206x over previous
//
#include <hip/hip_runtime.h>
#include <stdint.h>
#include <stddef.h>

typedef _Float16 f16;
typedef _Float16 half8 __attribute__((ext_vector_type(8)));
typedef _Float16 half4 __attribute__((ext_vector_type(4)));
typedef float floatx4 __attribute__((ext_vector_type(4)));

__device__ __forceinline__ floatx4 mfma16(half8 a, half8 b, floatx4 c) {
    return __builtin_amdgcn_mfma_f32_16x16x32_f16(a, b, c, 0, 0, 0);
}

typedef __attribute__((address_space(3))) void       lds_void_t;
typedef const __attribute__((address_space(1))) void gconst_void_t;

// async 16B/lane global->LDS; lds dest = wave-uniform base + lane*16
__device__ __forceinline__ void async_copy16(void* lds, const void* g) {
    __builtin_amdgcn_global_load_lds((gconst_void_t*)g, (lds_void_t*)lds, 16, 0, 0);
}

// ---------------- fused pre-pass ----------------
// blocks [0,2048): convert x f32->f16 row-major
// blocks [2048,2816): transpose w_attn [1024,3072] -> wattnT [3072,1024] f16
// blocks [2816,3072): transpose w_proj [1024,1024] -> wprojT [1024,1024] f16
__global__ __launch_bounds__(256)
void prepass(const float* __restrict__ x, const float* __restrict__ w_attn,
             const float* __restrict__ w_proj,
             f16* __restrict__ xh, f16* __restrict__ wattnT, f16* __restrict__ wprojT)
{
    __shared__ __align__(16) f16 t[64][72];
    const int bid = blockIdx.x;
    if (bid < 2048) {
        const size_t i = ((size_t)bid * 256 + threadIdx.x) * 8;
        floatx4 a = *(const floatx4*)(x + i);
        floatx4 b = *(const floatx4*)(x + i + 4);
        half8 h;
        h[0]=(f16)a[0]; h[1]=(f16)a[1]; h[2]=(f16)a[2]; h[3]=(f16)a[3];
        h[4]=(f16)b[0]; h[5]=(f16)b[1]; h[6]=(f16)b[2]; h[7]=(f16)b[3];
        *(half8*)(xh + i) = h;
        return;
    }
    const float* W; f16* WT; int Nsz, bx, by;
    if (bid < 2816) {
        W = w_attn; WT = wattnT; Nsz = 3072;
        const int r = bid - 2048; by = r / 48; bx = r - by * 48;
    } else {
        W = w_proj; WT = wprojT; Nsz = 1024;
        const int r = bid - 2816; by = r >> 4; bx = r & 15;
    }
    const int k0 = by << 6;
    const int n0 = bx << 6;
    {
        const int r  = threadIdx.x >> 2;
        const int c0 = (threadIdx.x & 3) << 4;
        #pragma unroll
        for (int i = 0; i < 4; ++i) {
            const int c = c0 + (i << 2);
            floatx4 v = *(const floatx4*)(W + (size_t)(k0 + r) * Nsz + n0 + c);
            t[c + 0][r] = (f16)v[0];
            t[c + 1][r] = (f16)v[1];
            t[c + 2][r] = (f16)v[2];
            t[c + 3][r] = (f16)v[3];
        }
    }
    __syncthreads();
    {
        const int n  = threadIdx.x >> 2;
        const int kc = (threadIdx.x & 3) << 4;
        #pragma unroll
        for (int i = 0; i < 2; ++i) {
            half8 h = *(half8*)&t[n][kc + (i << 3)];
            *(half8*)(WT + (size_t)(n0 + n) * 1024 + k0 + kc + (i << 3)) = h;
        }
    }
}

// ---------------- QKV GEMM ----------------
// R12: BK=64 x counted-vmcnt raw-barrier dbuf — the untested cell of the 2x2.
// Per iter (16 iters, half of BK=32): stage(buf^1) [8 copies] -> vmcnt(8)
// [prev 8 landed, new 8 IN FLIGHT through the whole iter] -> s_barrier ->
// 16 ds_read_b128 -> lgkmcnt(0)+sched_barrier -> s_barrier -> 32 MFMA.
// 128B rows would be 16-way bank conflict -> R5's correctness-proven XOR
// chunk-swizzle: LDS (row,c8) holds global chunk c8^(row&7); DMA source
// pre-swizzled (lane L: row lr=L>>3, chunk (L&7)^lr), LDS dest linear;
// reads use ((kk*4+quad)^(l16&7)). Epilogue: R2-coalesced stores.
__global__ __launch_bounds__(256, 2)
void gemm_qkv(const f16* __restrict__ A, const f16* __restrict__ BT,
              const float* __restrict__ bias, f16* __restrict__ QKV)
{
    __shared__ __align__(16) f16 As[2][128 * 64];
    __shared__ __align__(16) f16 Bs[2][128 * 64];

    const int tid  = threadIdx.x;
    const int wave = tid >> 6;
    const int lane = tid & 63;
    const int quad = lane >> 4;
    const int l16  = lane & 15;
    const int wm   = (wave >> 1) * 64;
    const int wn   = (wave & 1) * 64;
    const int m0   = blockIdx.y * 128;
    const int n0   = blockIdx.x * 128;
    const int Ksz  = 1024;

    // staging: copy g covers 8 rows x 64 cols; lane L -> row lr=L>>3,
    // source chunk csw=(L&7)^lr (XOR pre-swizzle, LDS dest linear).
    const int lr  = lane >> 3;
    const int csw = (lane & 7) ^ lr;

    const f16* AbS = A  + (size_t)(m0 + wave * 16 + lr) * Ksz + csw * 8;
    const f16* BbS = BT + (size_t)(n0 + wave * 16 + lr) * Ksz + csw * 8;

    auto stage = [&](int buf, int kc) {
        f16* AsW = &As[buf][(wave * 16) * 64];
        f16* BsW = &Bs[buf][(wave * 16) * 64];
        #pragma unroll
        for (int h = 0; h < 2; ++h)
            #pragma unroll
            for (int c = 0; c < 2; ++c) {
                const int ro = h * 64 + c * 8;   // rows wave*16+{0,8} and +64
                async_copy16(AsW + ro * 64, AbS + (size_t)ro * Ksz + kc);
                async_copy16(BsW + ro * 64, BbS + (size_t)ro * Ksz + kc);
            }
    };

    floatx4 acc[4][4] = {};

    stage(0, 0);   // 8 loads in flight

    int buf = 0;
    for (int kc = 0; kc < Ksz; kc += 64) {
        if (kc + 64 < Ksz) {
            stage(buf ^ 1, kc + 64);                          // 16 in flight
            asm volatile("s_waitcnt vmcnt(8)" ::: "memory");  // prev 8 landed
        } else {
            asm volatile("s_waitcnt vmcnt(0)" ::: "memory");
        }
        __builtin_amdgcn_sched_barrier(0);
        __builtin_amdgcn_s_barrier();          // buf readable by all waves
        __builtin_amdgcn_sched_barrier(0);

        half8 a[2][4], b[2][4];
        #pragma unroll
        for (int kk = 0; kk < 2; ++kk) {
            #pragma unroll
            for (int mt = 0; mt < 4; ++mt) {
                const int row = wm + mt * 16 + l16;
                a[kk][mt] = *(const half8*)&As[buf][row * 64
                            + ((((kk << 2) + quad) ^ (l16 & 7)) << 3)];
            }
            #pragma unroll
            for (int nt = 0; nt < 4; ++nt) {
                const int row = wn + nt * 16 + l16;
                b[kk][nt] = *(const half8*)&Bs[buf][row * 64
                            + ((((kk << 2) + quad) ^ (l16 & 7)) << 3)];
            }
        }
        asm volatile("s_waitcnt lgkmcnt(0)" ::: "memory");   // reads retired
        __builtin_amdgcn_sched_barrier(0);
        __builtin_amdgcn_s_barrier();          // buf free for next iter's DMA

        #pragma unroll
        for (int kk = 0; kk < 2; ++kk)
            #pragma unroll
            for (int mt = 0; mt < 4; ++mt)
                #pragma unroll
                for (int nt = 0; nt < 4; ++nt)
                    acc[mt][nt] = mfma16(a[kk][mt], b[kk][nt], acc[mt][nt]);
        buf ^= 1;
    }

    const size_t HSZ = (size_t)32 * 2048 * 64;   // one of Q/K/V regions
    #pragma unroll
    for (int mt = 0; mt < 4; ++mt) {
        #pragma unroll
        for (int nt = 0; nt < 4; ++nt) {
            const int col  = n0 + wn + nt * 16 + l16;
            const float bv = bias[col];
            const int row0 = m0 + wm + mt * 16 + (quad << 2);
            const int bb   = row0 >> 11;
            const int t0   = row0 & 2047;
            const int hh   = (col >> 6) & 15;
            const int d    = col & 63;
            float v0 = acc[mt][nt][0] + bv;
            float v1 = acc[mt][nt][1] + bv;
            float v2 = acc[mt][nt][2] + bv;
            float v3 = acc[mt][nt][3] + bv;
            if (col < 2048) {   // Q or K: [bh][t][d]
                f16* dst = QKV + (size_t)(col >> 10) * HSZ
                         + (((size_t)(bb * 16 + hh) * 2048 + t0) << 6) + d;
                dst[0]   = (f16)v0;
                dst[64]  = (f16)v1;
                dst[128] = (f16)v2;
                dst[192] = (f16)v3;
            } else {            // V^T: [bh][d][t], 4 consecutive t -> half4
                half4 h; h[0]=(f16)v0; h[1]=(f16)v1; h[2]=(f16)v2; h[3]=(f16)v3;
                *(half4*)(QKV + 2 * HSZ
                          + (((size_t)(bb * 16 + hh) << 6) + d) * 2048 + t0) = h;
            }
        }
    }
}

// ---------------- proj GEMM: 128x64 tile (512 blocks = 2/CU) ----------------
// R12: same BK=64 counted-vmcnt raw-barrier loop (6 copies/stage -> vmcnt(6)).
__global__ __launch_bounds__(256, 2)
void gemm_proj(const f16* __restrict__ A, const f16* __restrict__ BT,
               const float* __restrict__ bias, float* __restrict__ C)
{
    __shared__ __align__(16) f16 As[2][128 * 64];
    __shared__ __align__(16) f16 Bs[2][64 * 64];

    const int tid  = threadIdx.x;
    const int wave = tid >> 6;
    const int lane = tid & 63;
    const int quad = lane >> 4;
    const int l16  = lane & 15;
    const int wm   = (wave >> 1) * 64;
    const int wn   = (wave & 1) * 32;
    const int m0   = blockIdx.y * 128;
    const int n0   = blockIdx.x * 64;
    const int Ksz  = 1024;

    const int lr  = lane >> 3;
    const int csw = (lane & 7) ^ lr;

    const f16* AbS = A  + (size_t)(m0 + wave * 16 + lr) * Ksz + csw * 8;
    const f16* BbS = BT + (size_t)(n0 + wave * 16 + lr) * Ksz + csw * 8;

    auto stage = [&](int buf, int kc) {
        f16* AsW = &As[buf][(wave * 16) * 64];
        f16* BsW = &Bs[buf][(wave * 16) * 64];
        #pragma unroll
        for (int h = 0; h < 2; ++h)
            #pragma unroll
            for (int c = 0; c < 2; ++c) {
                const int ro = h * 64 + c * 8;
                async_copy16(AsW + ro * 64, AbS + (size_t)ro * Ksz + kc);
            }
        #pragma unroll
        for (int c = 0; c < 2; ++c) {
            const int ro = c * 8;               // B: 64 rows, 16 per wave
            async_copy16(BsW + ro * 64, BbS + (size_t)ro * Ksz + kc);
        }
    };

    floatx4 acc[4][2] = {};

    stage(0, 0);   // 6 loads in flight

    int buf = 0;
    for (int kc = 0; kc < Ksz; kc += 64) {
        if (kc + 64 < Ksz) {
            stage(buf ^ 1, kc + 64);                          // 12 in flight
            asm volatile("s_waitcnt vmcnt(6)" ::: "memory");  // prev 6 landed
        } else {
            asm volatile("s_waitcnt vmcnt(0)" ::: "memory");
        }
        __builtin_amdgcn_sched_barrier(0);
        __builtin_amdgcn_s_barrier();
        __builtin_amdgcn_sched_barrier(0);

        half8 a[2][4], b[2][2];
        #pragma unroll
        for (int kk = 0; kk < 2; ++kk) {
            #pragma unroll
            for (int mt = 0; mt < 4; ++mt) {
                const int row = wm + mt * 16 + l16;
                a[kk][mt] = *(const half8*)&As[buf][row * 64
                            + ((((kk << 2) + quad) ^ (l16 & 7)) << 3)];
            }
            #pragma unroll
            for (int nt = 0; nt < 2; ++nt) {
                const int row = wn + nt * 16 + l16;
                b[kk][nt] = *(const half8*)&Bs[buf][row * 64
                            + ((((kk << 2) + quad) ^ (l16 & 7)) << 3)];
            }
        }
        asm volatile("s_waitcnt lgkmcnt(0)" ::: "memory");
        __builtin_amdgcn_sched_barrier(0);
        __builtin_amdgcn_s_barrier();

        #pragma unroll
        for (int kk = 0; kk < 2; ++kk)
            #pragma unroll
            for (int mt = 0; mt < 4; ++mt)
                #pragma unroll
                for (int nt = 0; nt < 2; ++nt)
                    acc[mt][nt] = mfma16(a[kk][mt], b[kk][nt], acc[mt][nt]);
        buf ^= 1;
    }

    #pragma unroll
    for (int mt = 0; mt < 4; ++mt) {
        #pragma unroll
        for (int nt = 0; nt < 2; ++nt) {
            const int col  = n0 + wn + nt * 16 + l16;
            const float bv = bias[col];
            #pragma unroll
            for (int r = 0; r < 4; ++r) {
                const int row = m0 + wm + mt * 16 + (quad << 2) + r;
                C[(size_t)row * 1024 + col] = acc[mt][nt][r] + bv;
            }
        }
    }
}

// ---------------- Flash attention, causal — FUSED DUAL-TILE COMPUTE (R8) ------
// Serial-instance law (fits R7-R11): time = per-CU chain instances x chain cost
// (34 dual-chains x ~3700cy = 52.4us). compute2() processes BOTH q-tiles in one
// chain; adjacent pairing (jA=2g, jB=2g+1); CU balance: blocks g and 15-g.
// bh-fastest grid (XCD-confined K/V), Vt 4-buf DMA 2 ahead, barrier per 2
// chunks, setprio around MFMA, swizzled V/P LDS.
__global__ __launch_bounds__(256, 2)
void attn_fwd(const f16* __restrict__ Qb, const f16* __restrict__ Kb,
              const f16* __restrict__ Vb, f16* __restrict__ attn_out)
{
    const int bh   = blockIdx.x;     // 0..31
    const int yy   = blockIdx.y;     // 0..15
    const int g    = (yy < 8) ? yy : 23 - yy;   // group 0..15; CU-pair g with 15-g
    const int jA   = 2 * g;          // even q-tile
    const int jB   = 2 * g + 1;      // odd q-tile (scan length)
    const int head = bh & 15;
    const int b    = bh >> 4;
    const int tid  = threadIdx.x;
    const int wave = tid >> 6;
    const int lane = tid & 63;
    const int quad = lane >> 4;
    const int l16  = lane & 15;

    __shared__ __align__(16) f16 Vt[4][64 * 64];   // [buf][d][kv], kv chunk8 ^ (d&7)
    __shared__ __align__(16) f16 PsB[4][16 * 64];  // per-wave P[q][kv] for tile B
    __shared__ __align__(16) f16 PsA[4][16 * 64];  // per-wave P[q][kv] for tile A

    const f16* Qh = Qb + ((size_t)bh << 17);
    const f16* Kh = Kb + ((size_t)bh << 17);
    const f16* Vh = Vb + ((size_t)bh << 17);

    // V DMA: wave stages d rows 16w..16w+15; instr g covers rows +8g..+8g+7.
    // lane L -> d-row r8=L>>3, source kv-chunk c8=(L&7)^r8 (XOR-swizzled LDS).
    const int r8 = lane >> 3;
    const int c8 = (lane & 7) ^ r8;
    const f16* vsrcA = Vh + (size_t)(wave * 16 + r8) * 2048 + c8 * 8;
    const f16* vsrcB = vsrcA + (size_t)8 * 2048;

    half8 kf[8], kn[8];
    half8 qA0, qA1, qB0, qB1;
    floatx4 oA[4], oB[4];
    float lpA, lpB;

    auto loadK = [&](int kv0, half8* dst) {
        const f16* kp = Kh + (size_t)(kv0 + l16) * 64 + (quad << 3);
        #pragma unroll
        for (int t = 0; t < 4; ++t) {
            dst[2 * t]     = *(const half8*)(kp + t * 16 * 64);
            dst[2 * t + 1] = *(const half8*)(kp + t * 16 * 64 + 32);
        }
    };
    auto dmaV = [&](int kv0, int buf) {
        async_copy16(&Vt[buf][(wave * 16) * 64],     vsrcA + kv0);
        async_copy16(&Vt[buf][(wave * 16 + 8) * 64], vsrcB + kv0);
    };

    const int sw = l16 & 7;   // swizzle key (= d&7 and q&7 for our rows)

    // BOTH q-tiles in one chain: interleaved QK, one lgkm wait, shared V frags.
    // Precondition: kc < jB (tile B never diagonal here); diagA = (kc == jA).
    auto compute2 = [&](int kc, bool diagA, half8* kcur) {
        floatx4 sB[4] = {};
        floatx4 sA[4] = {};
        __builtin_amdgcn_s_setprio(1);
        #pragma unroll
        for (int t = 0; t < 4; ++t) {
            sB[t] = mfma16(kcur[2 * t],     qB0, sB[t]);
            sA[t] = mfma16(kcur[2 * t],     qA0, sA[t]);
            sB[t] = mfma16(kcur[2 * t + 1], qB1, sB[t]);
            sA[t] = mfma16(kcur[2 * t + 1], qA1, sA[t]);
        }
        __builtin_amdgcn_s_setprio(0);
        const int qrel = (wave << 4) + l16;
        #pragma unroll
        for (int t = 0; t < 4; ++t) {
            const int c = t * 2 + (quad >> 1);
            const int po = (l16 << 6) + ((c ^ sw) << 3) + ((quad & 1) << 2);
            float b0 = __builtin_amdgcn_exp2f(sB[t][0]);
            float b1 = __builtin_amdgcn_exp2f(sB[t][1]);
            float b2 = __builtin_amdgcn_exp2f(sB[t][2]);
            float b3 = __builtin_amdgcn_exp2f(sB[t][3]);
            lpB += (b0 + b1) + (b2 + b3);
            half4 pkB; pkB[0]=(f16)b0; pkB[1]=(f16)b1; pkB[2]=(f16)b2; pkB[3]=(f16)b3;
            *(half4*)&PsB[wave][po] = pkB;
            float a0 = __builtin_amdgcn_exp2f(sA[t][0]);
            float a1 = __builtin_amdgcn_exp2f(sA[t][1]);
            float a2 = __builtin_amdgcn_exp2f(sA[t][2]);
            float a3 = __builtin_amdgcn_exp2f(sA[t][3]);
            if (diagA) {
                const int kvb = t * 16 + (quad << 2);
                a0 = (kvb     <= qrel) ? a0 : 0.f;
                a1 = (kvb + 1 <= qrel) ? a1 : 0.f;
                a2 = (kvb + 2 <= qrel) ? a2 : 0.f;
                a3 = (kvb + 3 <= qrel) ? a3 : 0.f;
            }
            lpA += (a0 + a1) + (a2 + a3);
            half4 pkA; pkA[0]=(f16)a0; pkA[1]=(f16)a1; pkA[2]=(f16)a2; pkA[3]=(f16)a3;
            *(half4*)&PsA[wave][po] = pkA;
        }
        asm volatile("s_waitcnt lgkmcnt(0)" ::: "memory");
        half8 pB0 = *(const half8*)&PsB[wave][(l16 << 6) + (((quad    ) ^ sw) << 3)];
        half8 pB1 = *(const half8*)&PsB[wave][(l16 << 6) + (((quad + 4) ^ sw) << 3)];
        half8 pA0 = *(const half8*)&PsA[wave][(l16 << 6) + (((quad    ) ^ sw) << 3)];
        half8 pA1 = *(const half8*)&PsA[wave][(l16 << 6) + (((quad + 4) ^ sw) << 3)];
        const f16* vbuf = &Vt[kc & 3][0];
        __builtin_amdgcn_s_setprio(1);
        #pragma unroll
        for (int dt = 0; dt < 4; ++dt) {
            const f16* vrow = vbuf + ((dt * 16 + l16) << 6);
            half8 vf0 = *(const half8*)(vrow + (((quad    ) ^ sw) << 3));
            half8 vf1 = *(const half8*)(vrow + (((quad + 4) ^ sw) << 3));
            oB[dt] = mfma16(pB0, vf0, oB[dt]);
            oA[dt] = mfma16(pA0, vf0, oA[dt]);
            oB[dt] = mfma16(pB1, vf1, oB[dt]);
            oA[dt] = mfma16(pA1, vf1, oA[dt]);
        }
        __builtin_amdgcn_s_setprio(0);
    };

    // single-tile chunk (B-only tail), diag = (kc == jB)
    auto compute1 = [&](int kc, half8* kcur) {
        floatx4 s[4] = {};
        __builtin_amdgcn_s_setprio(1);
        #pragma unroll
        for (int t = 0; t < 4; ++t) {
            s[t] = mfma16(kcur[2 * t],     qB0, s[t]);
            s[t] = mfma16(kcur[2 * t + 1], qB1, s[t]);
        }
        __builtin_amdgcn_s_setprio(0);
        const bool diag = (kc == jB);
        const int qrel = (wave << 4) + l16;
        #pragma unroll
        for (int t = 0; t < 4; ++t) {
            float p0 = __builtin_amdgcn_exp2f(s[t][0]);
            float p1 = __builtin_amdgcn_exp2f(s[t][1]);
            float p2 = __builtin_amdgcn_exp2f(s[t][2]);
            float p3 = __builtin_amdgcn_exp2f(s[t][3]);
            if (diag) {
                const int kvb = t * 16 + (quad << 2);
                p0 = (kvb     <= qrel) ? p0 : 0.f;
                p1 = (kvb + 1 <= qrel) ? p1 : 0.f;
                p2 = (kvb + 2 <= qrel) ? p2 : 0.f;
                p3 = (kvb + 3 <= qrel) ? p3 : 0.f;
            }
            lpB += (p0 + p1) + (p2 + p3);
            half4 pk; pk[0]=(f16)p0; pk[1]=(f16)p1; pk[2]=(f16)p2; pk[3]=(f16)p3;
            const int c = t * 2 + (quad >> 1);
            *(half4*)&PsB[wave][(l16 << 6) + ((c ^ sw) << 3) + ((quad & 1) << 2)] = pk;
        }
        asm volatile("s_waitcnt lgkmcnt(0)" ::: "memory");
        half8 pf0 = *(const half8*)&PsB[wave][(l16 << 6) + (((quad    ) ^ sw) << 3)];
        half8 pf1 = *(const half8*)&PsB[wave][(l16 << 6) + (((quad + 4) ^ sw) << 3)];
        const f16* vbuf = &Vt[kc & 3][0];
        __builtin_amdgcn_s_setprio(1);
        #pragma unroll
        for (int dt = 0; dt < 4; ++dt) {
            const f16* vrow = vbuf + ((dt * 16 + l16) << 6);
            half8 vf0 = *(const half8*)(vrow + (((quad    ) ^ sw) << 3));
            half8 vf1 = *(const half8*)(vrow + (((quad + 4) ^ sw) << 3));
            oB[dt] = mfma16(pf0, vf0, oB[dt]);
            oB[dt] = mfma16(pf1, vf1, oB[dt]);
        }
        __builtin_amdgcn_s_setprio(0);
    };

    const f16 qs = (f16)0.1803368801f;   // (1/8) * log2(e)
    auto loadQ = [&](int j, half8& q0, half8& q1) {
        const f16* qp = Qh + (size_t)(j * 64 + wave * 16 + l16) * 64 + (quad << 3);
        q0 = *(const half8*)qp;
        q1 = *(const half8*)(qp + 32);
        #pragma unroll
        for (int i = 0; i < 8; ++i) { q0[i] *= qs; q1[i] *= qs; }
    };

    loadQ(jA, qA0, qA1);
    loadQ(jB, qB0, qB1);
    oA[0]=oA[1]=oA[2]=oA[3] = (floatx4){0.f,0.f,0.f,0.f};
    oB[0]=oB[1]=oB[2]=oB[3] = (floatx4){0.f,0.f,0.f,0.f};
    lpA = 0.f; lpB = 0.f;

    const int nB = jB + 1;   // = 2g+2 >= 2, always even
    loadK(0, kf);
    dmaV(0, 0);
    dmaV(64, 1);

    // pair loop: one barrier per TWO chunks; DMA chunks kc+2/kc+3 at pair top.
    // Even kc <= jA always -> compute2 (diagA iff kc==jA). Odd kc+1: compute2
    // while kc+1 <= jA (never diagonal, parity), else compute1 (B diag tail).
    for (int kc = 0; kc < nB; kc += 2) {
        __syncthreads();
        if (kc + 2 < nB) dmaV((kc + 2) << 6, (kc + 2) & 3);
        if (kc + 3 < nB) dmaV((kc + 3) << 6, (kc + 3) & 3);
        if (kc + 1 < nB) loadK((kc + 1) << 6, kn);
        compute2(kc, kc == jA, kf);
        if (kc + 1 < nB) {
            if (kc + 2 < nB) loadK((kc + 2) << 6, kf);
            if (kc + 1 <= jA) compute2(kc + 1, false, kn);
            else               compute1(kc + 1, kn);
        }
    }

    // epilogue per q-tile: reduce l over quads, transpose inv via shuffles, write O
    auto writeO = [&](int j, floatx4* o, float lp) {
        float l = lp;
        l += __shfl_xor(l, 16);
        l += __shfl_xor(l, 32);
        const float inv = 1.f / l;
        const int qrow0 = j * 64 + wave * 16;
        #pragma unroll
        for (int r = 0; r < 4; ++r) {
            const float invr = __shfl(inv, (quad << 2) + r);
            const int row = (b << 11) + qrow0 + (quad << 2) + r;
            f16* op = attn_out + (size_t)row * 1024 + head * 64 + l16;
            #pragma unroll
            for (int dt = 0; dt < 4; ++dt)
                op[dt * 16] = (f16)(o[dt][r] * invr);
        }
    };
    writeO(jB, oB, lpB);
    writeO(jA, oA, lpA);
}

extern "C" void kernel_launch(void* const* d_in, const int* in_sizes, int n_in,
                              void* d_out, int out_size, void* d_ws, size_t ws_size,
                              hipStream_t stream)
{
    const float* x      = (const float*)d_in[0];
    const float* w_attn = (const float*)d_in[1];
    const float* b_attn = (const float*)d_in[2];
    const float* w_proj = (const float*)d_in[3];
    const float* b_proj = (const float*)d_in[4];
    float* y = (float*)d_out;

    f16* xh       = (f16*)d_ws;                         // [4096,1024]
    f16* wattnT   = xh + (size_t)4096 * 1024;           // [3072,1024]
    f16* wprojT   = wattnT + (size_t)3072 * 1024;       // [1024,1024]
    f16* qkv      = wprojT + (size_t)1024 * 1024;       // Q,K: [32][2048][64]; V: [32][64][2048]
    f16* attn_out = qkv + (size_t)3 * 32 * 2048 * 64;   // [4096,1024]

    const size_t HSZ = (size_t)32 * 2048 * 64;

    prepass<<<dim3(3072), dim3(256), 0, stream>>>(x, w_attn, w_proj, xh, wattnT, wprojT);
    gemm_qkv<<<dim3(24, 32), dim3(256), 0, stream>>>(xh, wattnT, b_attn, qkv);
    attn_fwd<<<dim3(32, 16), dim3(256), 0, stream>>>(qkv, qkv + HSZ, qkv + 2 * HSZ, attn_out);
    gemm_proj<<<dim3(16, 32), dim3(256), 0, stream>>>(attn_out, wprojT, b_proj, y);
}